// Round 1
// baseline (829.102 us; speedup 1.0000x reference)
//
#include <hip/hip_runtime.h>
#include <math.h>

#define B_   2
#define LQ_  10723
#define D_   256
#define NH_  8
#define HD_  32
#define NL_  4
#define NP_  4
#define DFF_ 1024
#define M_   (B_ * LQ_)   // 21446

// ---------------------------------------------------------------------------
// elementwise add: c = a + b
// ---------------------------------------------------------------------------
__global__ __launch_bounds__(256) void add_kernel(const float* __restrict__ a,
                                                  const float* __restrict__ b,
                                                  float* __restrict__ c, size_t n) {
    size_t i = (size_t)blockIdx.x * 256 + threadIdx.x;
    if (i < n) c[i] = a[i] + b[i];
}

// ---------------------------------------------------------------------------
// C[M,N] = A[M,K] @ B[K,N] + bias[N]  (optional relu)
// 64x64 tile, 16 K-step, 256 threads, 4x4 register blocking. fp32.
// N must be a multiple of 64, K a multiple of 16.
// ---------------------------------------------------------------------------
__global__ __launch_bounds__(256) void gemm_bias_kernel(
    const float* __restrict__ A, const float* __restrict__ Bw,
    const float* __restrict__ bias, float* __restrict__ C,
    int M, int N, int K, int relu)
{
    __shared__ float As[64][17];   // +1 pad: kills 4-way bank conflict on column reads
    __shared__ float Bs[16][64];

    const int tid = threadIdx.x;
    const int tx = tid & 15, ty = tid >> 4;
    const int m0 = blockIdx.y * 64, n0 = blockIdx.x * 64;

    const int arow = tid >> 2;          // 0..63
    const int acol = (tid & 3) * 4;     // 0,4,8,12
    const int brow = tid >> 4;          // 0..15
    const int bcol = (tid & 15) * 4;    // 0..60

    float acc[4][4] = {};

    for (int k0 = 0; k0 < K; k0 += 16) {
        float4 av = make_float4(0.f, 0.f, 0.f, 0.f);
        int gr = m0 + arow;
        if (gr < M) av = *reinterpret_cast<const float4*>(A + (size_t)gr * K + k0 + acol);
        As[arow][acol + 0] = av.x; As[arow][acol + 1] = av.y;
        As[arow][acol + 2] = av.z; As[arow][acol + 3] = av.w;

        float4 bv = *reinterpret_cast<const float4*>(Bw + (size_t)(k0 + brow) * N + n0 + bcol);
        *reinterpret_cast<float4*>(&Bs[brow][bcol]) = bv;

        __syncthreads();
        #pragma unroll
        for (int kk = 0; kk < 16; ++kk) {
            float a0 = As[ty * 4 + 0][kk], a1 = As[ty * 4 + 1][kk];
            float a2 = As[ty * 4 + 2][kk], a3 = As[ty * 4 + 3][kk];
            float b0 = Bs[kk][tx * 4 + 0], b1 = Bs[kk][tx * 4 + 1];
            float b2 = Bs[kk][tx * 4 + 2], b3 = Bs[kk][tx * 4 + 3];
            acc[0][0] += a0 * b0; acc[0][1] += a0 * b1; acc[0][2] += a0 * b2; acc[0][3] += a0 * b3;
            acc[1][0] += a1 * b0; acc[1][1] += a1 * b1; acc[1][2] += a1 * b2; acc[1][3] += a1 * b3;
            acc[2][0] += a2 * b0; acc[2][1] += a2 * b1; acc[2][2] += a2 * b2; acc[2][3] += a2 * b3;
            acc[3][0] += a3 * b0; acc[3][1] += a3 * b1; acc[3][2] += a3 * b2; acc[3][3] += a3 * b3;
        }
        __syncthreads();
    }

    #pragma unroll
    for (int i = 0; i < 4; ++i) {
        int r = m0 + ty * 4 + i;
        if (r >= M) continue;
        #pragma unroll
        for (int j = 0; j < 4; ++j) {
            int c = n0 + tx * 4 + j;
            float v = acc[i][j] + bias[c];
            if (relu) v = fmaxf(v, 0.f);
            C[(size_t)r * N + c] = v;
        }
    }
}

// ---------------------------------------------------------------------------
// Multi-scale deformable attention core.
// One block per (b, lq); 256 threads = 8 heads x 32 HD lanes.
// off:   (M, 256)  layout [h][l][p][2]
// attnl: (M, 128)  layout [h][l*p]   (raw logits; softmax here)
// vproj: (M, 256)  head h occupies cols [h*32, h*32+32)
// refp:  (M, 8)    layout [l][2]  (x, y) normalized
// msout: (M, 256)  col = h*32 + d
// ---------------------------------------------------------------------------
__global__ __launch_bounds__(256) void msdeform_kernel(
    const float* __restrict__ vproj, const float* __restrict__ off,
    const float* __restrict__ attnl, const float* __restrict__ refp,
    float* __restrict__ msout)
{
    const int bq = blockIdx.x;            // b*LQ + lq
    const int b  = bq / LQ_;
    const int h  = threadIdx.x >> 5;
    const int d  = threadIdx.x & 31;

    // softmax over the 16 (level,point) logits for this head (redundant per lane)
    const float* lg = attnl + (size_t)bq * (NH_ * NL_ * NP_) + h * 16;
    float w[16];
    float mx = lg[0];
    #pragma unroll
    for (int i = 1; i < 16; ++i) mx = fmaxf(mx, lg[i]);
    float s = 0.f;
    #pragma unroll
    for (int i = 0; i < 16; ++i) { w[i] = expf(lg[i] - mx); s += w[i]; }
    const float inv = 1.f / s;

    const float* op = off + (size_t)bq * (NH_ * NL_ * NP_ * 2) + h * (NL_ * NP_ * 2);
    const float* rp = refp + (size_t)bq * (NL_ * 2);
    const float* vb = vproj + (size_t)b * LQ_ * D_ + h * HD_ + d;

    const int Hs[4] = {76, 38, 19, 10};
    const int Ws[4] = {106, 53, 27, 14};

    float acc = 0.f;
    int start = 0;
    #pragma unroll
    for (int l = 0; l < NL_; ++l) {
        const int H = Hs[l], W = Ws[l];
        const float rx = rp[l * 2 + 0], ry = rp[l * 2 + 1];
        #pragma unroll
        for (int p = 0; p < NP_; ++p) {
            const float ox = op[(l * NP_ + p) * 2 + 0];
            const float oy = op[(l * NP_ + p) * 2 + 1];
            const float lx = rx + ox / (float)W;
            const float ly = ry + oy / (float)H;
            const float x = lx * (float)W - 0.5f;
            const float y = ly * (float)H - 0.5f;
            const float x0f = floorf(x), y0f = floorf(y);
            const float fx = x - x0f, fy = y - y0f;
            const int x0 = (int)x0f, y0 = (int)y0f;
            const float aw = w[l * NP_ + p] * inv;
            #pragma unroll
            for (int dy = 0; dy < 2; ++dy) {
                const int yi = y0 + dy;
                const float wy = dy ? fy : 1.f - fy;
                const bool vy = (yi >= 0) && (yi < H);
                const int yc = min(max(yi, 0), H - 1);
                #pragma unroll
                for (int dx = 0; dx < 2; ++dx) {
                    const int xi = x0 + dx;
                    const float wx = dx ? fx : 1.f - fx;
                    const bool vx = (xi >= 0) && (xi < W);
                    const int xc = min(max(xi, 0), W - 1);
                    const float wgt = (vx && vy) ? (wx * wy * aw) : 0.f;
                    if (wgt != 0.f) {
                        acc += wgt * vb[(size_t)(start + yc * W + xc) * D_];
                    }
                }
            }
        }
        start += H * W;
    }
    msout[(size_t)bq * D_ + h * HD_ + d] = acc;
}

// ---------------------------------------------------------------------------
// out[row] = LayerNorm(a[row] + bsrc[row]) * g + beta   (row of 256)
// ---------------------------------------------------------------------------
__global__ __launch_bounds__(256) void add_ln_kernel(
    const float* __restrict__ a, const float* __restrict__ bsrc,
    const float* __restrict__ g, const float* __restrict__ beta,
    float* __restrict__ out)
{
    const int row = blockIdx.x;
    const int c = threadIdx.x;
    const size_t idx = (size_t)row * D_ + c;
    const float x = a[idx] + bsrc[idx];

    __shared__ float red[4];
    const int wid = c >> 6, lane = c & 63;

    float v = x;
    #pragma unroll
    for (int o = 32; o > 0; o >>= 1) v += __shfl_down(v, o, 64);
    if (lane == 0) red[wid] = v;
    __syncthreads();
    const float mean = (red[0] + red[1] + red[2] + red[3]) * (1.f / 256.f);
    const float dx = x - mean;

    float v2 = dx * dx;
    #pragma unroll
    for (int o = 32; o > 0; o >>= 1) v2 += __shfl_down(v2, o, 64);
    __syncthreads();
    if (lane == 0) red[wid] = v2;
    __syncthreads();
    const float var = (red[0] + red[1] + red[2] + red[3]) * (1.f / 256.f);

    out[idx] = dx * rsqrtf(var + 1e-5f) * g[c] + beta[c];
}

// ---------------------------------------------------------------------------
extern "C" void kernel_launch(void* const* d_in, const int* in_sizes, int n_in,
                              void* d_out, int out_size, void* d_ws, size_t ws_size,
                              hipStream_t stream) {
    const float* query = (const float*)d_in[0];
    const float* qpos  = (const float*)d_in[1];
    const float* value = (const float*)d_in[2];
    const float* refp  = (const float*)d_in[3];
    // d_in[4] spatial_shapes, d_in[5] level_start_index: static, baked in
    const float* W_off  = (const float*)d_in[6];
    const float* b_off  = (const float*)d_in[7];
    const float* W_attn = (const float*)d_in[8];
    const float* b_attn = (const float*)d_in[9];
    const float* W_v    = (const float*)d_in[10];
    const float* b_v    = (const float*)d_in[11];
    const float* W_out  = (const float*)d_in[12];
    const float* b_out  = (const float*)d_in[13];
    const float* ln1_g  = (const float*)d_in[14];
    const float* ln1_b  = (const float*)d_in[15];
    const float* W1     = (const float*)d_in[16];
    const float* b1     = (const float*)d_in[17];
    const float* W2     = (const float*)d_in[18];
    const float* b2     = (const float*)d_in[19];
    const float* ln2_g  = (const float*)d_in[20];
    const float* ln2_b  = (const float*)d_in[21];
    float* out = (float*)d_out;

    const size_t A = (size_t)M_ * D_;          // 5,490,176 floats
    float* ws = (float*)d_ws;
    float* P0 = ws;            // qbuf -> msout -> ffnout            (A)
    float* P1 = ws + A;        // vproj -> src2                      (A)
    float* P2 = ws + 2 * A;    // attn logits (M x 128) -> q1        (A)
    float* P3 = ws + 3 * A;    // off (A), later FFN hidden h (4A)   (4A)
    // total: 7A floats = ~154 MB

    const dim3 blk(256);
    auto grid_g = [](int M, int N) { return dim3((unsigned)(N / 64), (unsigned)((M + 63) / 64)); };

    // q = query + query_pos
    add_kernel<<<dim3((unsigned)((A + 255) / 256)), blk, 0, stream>>>(query, qpos, P0, A);
    // vproj = value @ W_v + b_v
    gemm_bias_kernel<<<grid_g(M_, 256), blk, 0, stream>>>(value, W_v, b_v, P1, M_, 256, 256, 0);
    // off = q @ W_off + b_off   (M x 256)
    gemm_bias_kernel<<<grid_g(M_, 256), blk, 0, stream>>>(P0, W_off, b_off, P3, M_, 256, 256, 0);
    // attn logits = q @ W_attn + b_attn  (M x 128)
    gemm_bias_kernel<<<grid_g(M_, 128), blk, 0, stream>>>(P0, W_attn, b_attn, P2, M_, 128, 256, 0);
    // msout = deformable attention (softmax + bilinear gather)
    msdeform_kernel<<<dim3(M_), blk, 0, stream>>>(P1, P3, P2, refp, P0);
    // src2 = msout @ W_out + b_out
    gemm_bias_kernel<<<grid_g(M_, 256), blk, 0, stream>>>(P0, W_out, b_out, P1, M_, 256, 256, 0);
    // q1 = LN(query + src2)
    add_ln_kernel<<<dim3(M_), blk, 0, stream>>>(query, P1, ln1_g, ln1_b, P2);
    // h = relu(q1 @ W1 + b1)   (M x 1024)
    gemm_bias_kernel<<<grid_g(M_, 1024), blk, 0, stream>>>(P2, W1, b1, P3, M_, 1024, 256, 1);
    // ffn = h @ W2 + b2
    gemm_bias_kernel<<<grid_g(M_, 256), blk, 0, stream>>>(P3, W2, b2, P0, M_, 256, 1024, 0);
    // out = LN(q1 + ffn)
    add_ln_kernel<<<dim3(M_), blk, 0, stream>>>(P2, P0, ln2_g, ln2_b, out);
}

// Round 2
// 497.787 us; speedup vs baseline: 1.6656x; 1.6656x over previous
//
#include <hip/hip_runtime.h>
#include <math.h>

#define B_   2
#define LQ_  10723
#define D_   256
#define NH_  8
#define HD_  32
#define NL_  4
#define NP_  4
#define DFF_ 1024
#define M_   (B_ * LQ_)   // 21446

typedef __attribute__((ext_vector_type(4))) float f32x4;
typedef __attribute__((ext_vector_type(8))) short short8;
typedef __attribute__((ext_vector_type(4))) unsigned short us4;

__device__ __forceinline__ unsigned short f2bf(float f) {
    union { float f; unsigned int u; } x; x.f = f;
    unsigned int r = x.u + 0x7FFF + ((x.u >> 16) & 1);   // RNE
    return (unsigned short)(r >> 16);
}

#define AS3U(p) ((__attribute__((address_space(3))) unsigned int*)(uintptr_t)(p))
#define AS1U(p) ((const __attribute__((address_space(1))) unsigned int*)(uintptr_t)(p))

// ---------------------------------------------------------------------------
// fp32 -> bf16 convert (vectorized), n must be multiple of 4
// ---------------------------------------------------------------------------
__global__ __launch_bounds__(256) void f32_to_bf16_kernel(
    const float* __restrict__ in, unsigned short* __restrict__ out, size_t n4) {
    size_t i = (size_t)blockIdx.x * 256 + threadIdx.x;
    if (i >= n4) return;
    float4 v = reinterpret_cast<const float4*>(in)[i];
    us4 r = { f2bf(v.x), f2bf(v.y), f2bf(v.z), f2bf(v.w) };
    reinterpret_cast<us4*>(out)[i] = r;
}

// q = bf16(query + query_pos), n multiple of 4
__global__ __launch_bounds__(256) void add_q_kernel(
    const float* __restrict__ a, const float* __restrict__ b,
    unsigned short* __restrict__ out, size_t n4) {
    size_t i = (size_t)blockIdx.x * 256 + threadIdx.x;
    if (i >= n4) return;
    float4 va = reinterpret_cast<const float4*>(a)[i];
    float4 vb = reinterpret_cast<const float4*>(b)[i];
    us4 r = { f2bf(va.x + vb.x), f2bf(va.y + vb.y), f2bf(va.z + vb.z), f2bf(va.w + vb.w) };
    reinterpret_cast<us4*>(out)[i] = r;
}

// W (K,N) f32 -> WT (N,K) bf16
__global__ __launch_bounds__(256) void transpose_bf16_kernel(
    const float* __restrict__ in, unsigned short* __restrict__ out, int K, int N) {
    int idx = blockIdx.x * 256 + threadIdx.x;
    if (idx >= K * N) return;
    int k = idx / N, n = idx - k * N;
    out[(size_t)n * K + k] = f2bf(in[idx]);
}

// ---------------------------------------------------------------------------
// MFMA bf16 GEMM: C[M,N] = A[M,K] @ BT[N,K]^T + bias[N]
// 128x128 tile, BK=32, 256 threads = 4 waves (2x2 of 64x64), m97 structure.
// N multiple of 128, K multiple of 32. M edge handled by clamp + pred store.
// ---------------------------------------------------------------------------
template<int RELU, int OUT_BF16>
__global__ __launch_bounds__(256) void gemm_mfma(
    const unsigned short* __restrict__ A,
    const unsigned short* __restrict__ BT,
    const float* __restrict__ bias,
    void* __restrict__ Cout,
    int M, int N, int K)
{
    __shared__ unsigned short As[128 * 32];
    __shared__ unsigned short Bs[128 * 32];

    const int tid  = threadIdx.x;
    const int wave = tid >> 6;
    const int lane = tid & 63;
    const int m0 = blockIdx.y * 128;
    const int n0 = blockIdx.x * 128;
    const int wr = (wave >> 1) * 64;
    const int wc = (wave & 1) * 64;

    f32x4 acc[4][4] = {};

    // staging: 2 passes x 256 threads x 16B per operand (8192 B tile)
    const int soff = wave * 1024 + lane * 16;   // byte offset within a 4096B pass

    for (int k0 = 0; k0 < K; k0 += 32) {
        __syncthreads();   // previous iter's ds_reads complete before overwrite
        #pragma unroll
        for (int p = 0; p < 2; ++p) {
            const int off  = p * 4096 + soff;   // 0..8191
            const int row  = off >> 6;          // 64 B per 32-bf16 row
            const int colb = off & 63;
            int ar = m0 + row; ar = (ar < M) ? ar : (M - 1);
            const unsigned short* asrc = A + (size_t)ar * K + k0 + (colb >> 1);
            __builtin_amdgcn_global_load_lds(AS1U(asrc),
                AS3U(As + ((p * 4096 + wave * 1024) >> 1)), 16, 0, 0);
            const unsigned short* bsrc = BT + (size_t)(n0 + row) * K + k0 + (colb >> 1);
            __builtin_amdgcn_global_load_lds(AS1U(bsrc),
                AS3U(Bs + ((p * 4096 + wave * 1024) >> 1)), 16, 0, 0);
        }
        __syncthreads();   // compiler drains vmcnt(0) before barrier

        const int fr = lane & 15;
        const int kb = (lane >> 4) * 8;
        short8 af[4], bf[4];
        #pragma unroll
        for (int m = 0; m < 4; ++m)
            af[m] = *reinterpret_cast<const short8*>(As + (wr + m * 16 + fr) * 32 + kb);
        #pragma unroll
        for (int n = 0; n < 4; ++n)
            bf[n] = *reinterpret_cast<const short8*>(Bs + (wc + n * 16 + fr) * 32 + kb);
        #pragma unroll
        for (int m = 0; m < 4; ++m)
            #pragma unroll
            for (int n = 0; n < 4; ++n)
                acc[m][n] = __builtin_amdgcn_mfma_f32_16x16x32_bf16(af[m], bf[n], acc[m][n], 0, 0, 0);
    }

    const int fr = lane & 15;
    const int r0 = (lane >> 4) * 4;
    #pragma unroll
    for (int n = 0; n < 4; ++n) {
        const int col = n0 + wc + n * 16 + fr;
        const float bv = bias[col];
        #pragma unroll
        for (int m = 0; m < 4; ++m) {
            #pragma unroll
            for (int r = 0; r < 4; ++r) {
                const int row = m0 + wr + m * 16 + r0 + r;
                if (row < M) {
                    float v = acc[m][n][r] + bv;
                    if (RELU) v = fmaxf(v, 0.f);
                    if (OUT_BF16)
                        ((unsigned short*)Cout)[(size_t)row * N + col] = f2bf(v);
                    else
                        ((float*)Cout)[(size_t)row * N + col] = v;
                }
            }
        }
    }
}

// ---------------------------------------------------------------------------
// Multi-scale deformable attention core (unchanged math; bf16 output).
// One block per (b, lq); 256 threads = 8 heads x 32 HD lanes.
// ---------------------------------------------------------------------------
__global__ __launch_bounds__(256) void msdeform_kernel(
    const float* __restrict__ vproj, const float* __restrict__ off,
    const float* __restrict__ attnl, const float* __restrict__ refp,
    unsigned short* __restrict__ msout)
{
    const int bq = blockIdx.x;
    const int b  = bq / LQ_;
    const int h  = threadIdx.x >> 5;
    const int d  = threadIdx.x & 31;

    const float* lg = attnl + (size_t)bq * (NH_ * NL_ * NP_) + h * 16;
    float w[16];
    float mx = lg[0];
    #pragma unroll
    for (int i = 1; i < 16; ++i) mx = fmaxf(mx, lg[i]);
    float s = 0.f;
    #pragma unroll
    for (int i = 0; i < 16; ++i) { w[i] = expf(lg[i] - mx); s += w[i]; }
    const float inv = 1.f / s;

    const float* op = off + (size_t)bq * (NH_ * NL_ * NP_ * 2) + h * (NL_ * NP_ * 2);
    const float* rp = refp + (size_t)bq * (NL_ * 2);
    const float* vb = vproj + (size_t)b * LQ_ * D_ + h * HD_ + d;

    const int Hs[4] = {76, 38, 19, 10};
    const int Ws[4] = {106, 53, 27, 14};

    float acc = 0.f;
    int start = 0;
    #pragma unroll
    for (int l = 0; l < NL_; ++l) {
        const int H = Hs[l], W = Ws[l];
        const float rx = rp[l * 2 + 0], ry = rp[l * 2 + 1];
        #pragma unroll
        for (int p = 0; p < NP_; ++p) {
            const float ox = op[(l * NP_ + p) * 2 + 0];
            const float oy = op[(l * NP_ + p) * 2 + 1];
            const float x = (rx + ox / (float)W) * (float)W - 0.5f;
            const float y = (ry + oy / (float)H) * (float)H - 0.5f;
            const float x0f = floorf(x), y0f = floorf(y);
            const float fx = x - x0f, fy = y - y0f;
            const int x0 = (int)x0f, y0 = (int)y0f;
            const float aw = w[l * NP_ + p] * inv;
            #pragma unroll
            for (int dy = 0; dy < 2; ++dy) {
                const int yi = y0 + dy;
                const float wy = dy ? fy : 1.f - fy;
                const bool vy = (yi >= 0) && (yi < H);
                const int yc = min(max(yi, 0), H - 1);
                #pragma unroll
                for (int dx = 0; dx < 2; ++dx) {
                    const int xi = x0 + dx;
                    const float wx = dx ? fx : 1.f - fx;
                    const bool vx = (xi >= 0) && (xi < W);
                    const int xc = min(max(xi, 0), W - 1);
                    const float wgt = (vx && vy) ? (wx * wy * aw) : 0.f;
                    if (wgt != 0.f)
                        acc += wgt * vb[(size_t)(start + yc * W + xc) * D_];
                }
            }
        }
        start += H * W;
    }
    msout[(size_t)bq * D_ + h * HD_ + d] = f2bf(acc);
}

// ---------------------------------------------------------------------------
// out = LayerNorm(a + bsrc) * g + beta; optional bf16 mirror for next GEMM
// ---------------------------------------------------------------------------
__global__ __launch_bounds__(256) void add_ln_kernel(
    const float* __restrict__ a, const float* __restrict__ bsrc,
    const float* __restrict__ g, const float* __restrict__ beta,
    float* __restrict__ out, unsigned short* __restrict__ out16)
{
    const int row = blockIdx.x;
    const int c = threadIdx.x;
    const size_t idx = (size_t)row * D_ + c;
    const float x = a[idx] + bsrc[idx];

    __shared__ float red[4];
    const int wid = c >> 6, lane = c & 63;

    float v = x;
    #pragma unroll
    for (int o = 32; o > 0; o >>= 1) v += __shfl_down(v, o, 64);
    if (lane == 0) red[wid] = v;
    __syncthreads();
    const float mean = (red[0] + red[1] + red[2] + red[3]) * (1.f / 256.f);
    const float dx = x - mean;

    float v2 = dx * dx;
    #pragma unroll
    for (int o = 32; o > 0; o >>= 1) v2 += __shfl_down(v2, o, 64);
    __syncthreads();
    if (lane == 0) red[wid] = v2;
    __syncthreads();
    const float var = (red[0] + red[1] + red[2] + red[3]) * (1.f / 256.f);

    const float y = dx * rsqrtf(var + 1e-5f) * g[c] + beta[c];
    out[idx] = y;
    if (out16) out16[idx] = f2bf(y);
}

// ---------------------------------------------------------------------------
extern "C" void kernel_launch(void* const* d_in, const int* in_sizes, int n_in,
                              void* d_out, int out_size, void* d_ws, size_t ws_size,
                              hipStream_t stream) {
    const float* query = (const float*)d_in[0];
    const float* qpos  = (const float*)d_in[1];
    const float* value = (const float*)d_in[2];
    const float* refp  = (const float*)d_in[3];
    const float* W_off  = (const float*)d_in[6];
    const float* b_off  = (const float*)d_in[7];
    const float* W_attn = (const float*)d_in[8];
    const float* b_attn = (const float*)d_in[9];
    const float* W_v    = (const float*)d_in[10];
    const float* b_v    = (const float*)d_in[11];
    const float* W_out  = (const float*)d_in[12];
    const float* b_out  = (const float*)d_in[13];
    const float* ln1_g  = (const float*)d_in[14];
    const float* ln1_b  = (const float*)d_in[15];
    const float* W1     = (const float*)d_in[16];
    const float* b1     = (const float*)d_in[17];
    const float* W2     = (const float*)d_in[18];
    const float* b2     = (const float*)d_in[19];
    const float* ln2_g  = (const float*)d_in[20];
    const float* ln2_b  = (const float*)d_in[21];
    float* out = (float*)d_out;

    // ---- workspace layout (bytes) ----
    uint8_t* w = (uint8_t*)d_ws;
    unsigned short* WvT   = (unsigned short*)(w);                 //  65536 us
    unsigned short* WoffT = WvT   + 65536;                        //  65536
    unsigned short* WattnT= WoffT + 65536;                        //  32768
    unsigned short* WoutT = WattnT+ 32768;                        //  65536
    unsigned short* W1T   = WoutT + 65536;                        // 262144
    unsigned short* W2T   = W1T   + 262144;                       // 262144
    uint8_t* base = (uint8_t*)(W2T + 262144);
    // round to 256B
    base = (uint8_t*)(((uintptr_t)base + 255) & ~(uintptr_t)255);

    const size_t A  = (size_t)M_ * D_;       // elems per (M,256)
    unsigned short* R1 = (unsigned short*)base;            // v16 -> q1b16   (2A bytes... A elems)
    unsigned short* R2 = R1 + A;                           // qb16 -> ms16
    float* R3 = (float*)(R2 + A);                          // vproj -> src2 -> ffn
    float* R4 = R3 + A;                                    // off -> q1
    float* R5 = R4 + A;                                    // attnl (M x 128)
    unsigned short* R6 = (unsigned short*)(R5 + A / 2);    // h16 (M x 1024)

    const dim3 blk(256);
    auto cdiv = [](size_t a, size_t b) { return (unsigned)((a + b - 1) / b); };

    // weight transpose+convert
    transpose_bf16_kernel<<<cdiv(256 * 256, 256), blk, 0, stream>>>(W_v,    WvT,    256, 256);
    transpose_bf16_kernel<<<cdiv(256 * 256, 256), blk, 0, stream>>>(W_off,  WoffT,  256, 256);
    transpose_bf16_kernel<<<cdiv(256 * 128, 256), blk, 0, stream>>>(W_attn, WattnT, 256, 128);
    transpose_bf16_kernel<<<cdiv(256 * 256, 256), blk, 0, stream>>>(W_out,  WoutT,  256, 256);
    transpose_bf16_kernel<<<cdiv(256 * 1024, 256), blk, 0, stream>>>(W1,    W1T,    256, 1024);
    transpose_bf16_kernel<<<cdiv(1024 * 256, 256), blk, 0, stream>>>(W2,    W2T,    1024, 256);

    // value -> bf16 ; q = bf16(query + qpos)
    f32_to_bf16_kernel<<<cdiv(A / 4, 256), blk, 0, stream>>>(value, R1, A / 4);
    add_q_kernel<<<cdiv(A / 4, 256), blk, 0, stream>>>(query, qpos, R2, A / 4);

    const unsigned MT = (M_ + 127) / 128;   // 168
    // vproj = v16 @ WvT^T (f32)
    gemm_mfma<0, 0><<<dim3(2, MT), blk, 0, stream>>>(R1, WvT, b_v, R3, M_, 256, 256);
    // off = qb @ WoffT^T (f32)
    gemm_mfma<0, 0><<<dim3(2, MT), blk, 0, stream>>>(R2, WoffT, b_off, R4, M_, 256, 256);
    // attnl = qb @ WattnT^T (f32)
    gemm_mfma<0, 0><<<dim3(1, MT), blk, 0, stream>>>(R2, WattnT, b_attn, R5, M_, 128, 256);
    // msout (bf16) -- overwrites R2 (qb16 dead)
    msdeform_kernel<<<dim3(M_), blk, 0, stream>>>(R3, R4, R5, refp, R2);
    // src2 = ms16 @ WoutT^T (f32) -- overwrites R3 (vproj dead)
    gemm_mfma<0, 0><<<dim3(2, MT), blk, 0, stream>>>(R2, WoutT, b_out, R3, M_, 256, 256);
    // q1 = LN(query + src2): f32 in R4 (off dead), bf16 in R1 (v16 dead)
    add_ln_kernel<<<dim3(M_), blk, 0, stream>>>(query, R3, ln1_g, ln1_b, R4, R1);
    // h = relu(q1b @ W1T^T) (bf16) in R6
    gemm_mfma<1, 1><<<dim3(8, MT), blk, 0, stream>>>(R1, W1T, b1, R6, M_, 1024, 256);
    // ffn = h @ W2T^T (f32) -- overwrites R3
    gemm_mfma<0, 0><<<dim3(2, MT), blk, 0, stream>>>(R6, W2T, b2, R3, M_, 256, 1024);
    // out = LN(q1 + ffn)
    add_ln_kernel<<<dim3(M_), blk, 0, stream>>>(R4, R3, ln2_g, ln2_b, out, nullptr);
}

// Round 3
// 269.144 us; speedup vs baseline: 3.0805x; 1.8495x over previous
//
#include <hip/hip_runtime.h>
#include <math.h>

#define B_   2
#define LQ_  10723
#define D_   256
#define NH_  8
#define HD_  32
#define NL_  4
#define NP_  4
#define DFF_ 1024
#define M_   (B_ * LQ_)   // 21446

typedef __attribute__((ext_vector_type(4))) float f32x4;
typedef __attribute__((ext_vector_type(8))) short short8;
typedef __attribute__((ext_vector_type(4))) unsigned short us4;

__device__ __forceinline__ unsigned short f2bf(float f) {
    union { float f; unsigned int u; } x; x.f = f;
    unsigned int r = x.u + 0x7FFF + ((x.u >> 16) & 1);   // RNE
    return (unsigned short)(r >> 16);
}
__device__ __forceinline__ float bf2f(unsigned short u) {
    union { unsigned int u; float f; } x; x.u = (unsigned int)u << 16;
    return x.f;
}

#define AS3U(p) ((__attribute__((address_space(3))) unsigned int*)(uintptr_t)(p))
#define AS1U(p) ((const __attribute__((address_space(1))) unsigned int*)(uintptr_t)(p))

// ---------------------------------------------------------------------------
__global__ __launch_bounds__(256) void f32_to_bf16_kernel(
    const float* __restrict__ in, unsigned short* __restrict__ out, size_t n4) {
    size_t i = (size_t)blockIdx.x * 256 + threadIdx.x;
    if (i >= n4) return;
    float4 v = reinterpret_cast<const float4*>(in)[i];
    us4 r = { f2bf(v.x), f2bf(v.y), f2bf(v.z), f2bf(v.w) };
    reinterpret_cast<us4*>(out)[i] = r;
}

__global__ __launch_bounds__(256) void add_q_kernel(
    const float* __restrict__ a, const float* __restrict__ b,
    unsigned short* __restrict__ out, size_t n4) {
    size_t i = (size_t)blockIdx.x * 256 + threadIdx.x;
    if (i >= n4) return;
    float4 va = reinterpret_cast<const float4*>(a)[i];
    float4 vb = reinterpret_cast<const float4*>(b)[i];
    us4 r = { f2bf(va.x + vb.x), f2bf(va.y + vb.y), f2bf(va.z + vb.z), f2bf(va.w + vb.w) };
    reinterpret_cast<us4*>(out)[i] = r;
}

// W (K,N) f32 -> WT (N,K) bf16
__global__ __launch_bounds__(256) void transpose_bf16_kernel(
    const float* __restrict__ in, unsigned short* __restrict__ out, int K, int N) {
    int idx = blockIdx.x * 256 + threadIdx.x;
    if (idx >= K * N) return;
    int k = idx / N, n = idx - k * N;
    out[(size_t)n * K + k] = f2bf(in[idx]);
}

// ---------------------------------------------------------------------------
// MFMA bf16 GEMM: C[M,N] = A[M,K] @ BT[N,K]^T + bias[N]   (m97 structure)
// ---------------------------------------------------------------------------
template<int RELU, int OUT_BF16>
__global__ __launch_bounds__(256) void gemm_mfma(
    const unsigned short* __restrict__ A,
    const unsigned short* __restrict__ BT,
    const float* __restrict__ bias,
    void* __restrict__ Cout,
    int M, int N, int K)
{
    __shared__ unsigned short As[128 * 32];
    __shared__ unsigned short Bs[128 * 32];

    const int tid  = threadIdx.x;
    const int wave = tid >> 6;
    const int lane = tid & 63;
    const int m0 = blockIdx.y * 128;
    const int n0 = blockIdx.x * 128;
    const int wr = (wave >> 1) * 64;
    const int wc = (wave & 1) * 64;

    f32x4 acc[4][4] = {};

    const int soff = wave * 1024 + lane * 16;

    for (int k0 = 0; k0 < K; k0 += 32) {
        __syncthreads();
        #pragma unroll
        for (int p = 0; p < 2; ++p) {
            const int off  = p * 4096 + soff;
            const int row  = off >> 6;
            const int colb = off & 63;
            int ar = m0 + row; ar = (ar < M) ? ar : (M - 1);
            const unsigned short* asrc = A + (size_t)ar * K + k0 + (colb >> 1);
            __builtin_amdgcn_global_load_lds(AS1U(asrc),
                AS3U(As + ((p * 4096 + wave * 1024) >> 1)), 16, 0, 0);
            const unsigned short* bsrc = BT + (size_t)(n0 + row) * K + k0 + (colb >> 1);
            __builtin_amdgcn_global_load_lds(AS1U(bsrc),
                AS3U(Bs + ((p * 4096 + wave * 1024) >> 1)), 16, 0, 0);
        }
        __syncthreads();

        const int fr = lane & 15;
        const int kb = (lane >> 4) * 8;
        short8 af[4], bf[4];
        #pragma unroll
        for (int m = 0; m < 4; ++m)
            af[m] = *reinterpret_cast<const short8*>(As + (wr + m * 16 + fr) * 32 + kb);
        #pragma unroll
        for (int n = 0; n < 4; ++n)
            bf[n] = *reinterpret_cast<const short8*>(Bs + (wc + n * 16 + fr) * 32 + kb);
        #pragma unroll
        for (int m = 0; m < 4; ++m)
            #pragma unroll
            for (int n = 0; n < 4; ++n)
                acc[m][n] = __builtin_amdgcn_mfma_f32_16x16x32_bf16(af[m], bf[n], acc[m][n], 0, 0, 0);
    }

    const int fr = lane & 15;
    const int r0 = (lane >> 4) * 4;
    #pragma unroll
    for (int n = 0; n < 4; ++n) {
        const int col = n0 + wc + n * 16 + fr;
        const float bv = bias[col];
        #pragma unroll
        for (int m = 0; m < 4; ++m) {
            #pragma unroll
            for (int r = 0; r < 4; ++r) {
                const int row = m0 + wr + m * 16 + r0 + r;
                if (row < M) {
                    float v = acc[m][n][r] + bv;
                    if (RELU) v = fmaxf(v, 0.f);
                    if (OUT_BF16)
                        ((unsigned short*)Cout)[(size_t)row * N + col] = f2bf(v);
                    else
                        ((float*)Cout)[(size_t)row * N + col] = v;
                }
            }
        }
    }
}

// ---------------------------------------------------------------------------
// Multi-scale deformable attention, restructured:
// one WAVE per query (4 queries / 256-thread block).
// Phase 1: lane -> (h = lane>>3, point-pair k = lane&7): softmax via 8-lane
//          shfl_xor, bilinear weights/indices once; store {int4,float4} to LDS.
// Phase 2: lane -> (h = lane>>3, ch-quad j = lane&7): 64 us4 gathers from
//          bf16 vproj, weight-FMA into float4 acc.
// No __syncthreads needed: LDS producer == consumer wave.
// ---------------------------------------------------------------------------
__global__ __launch_bounds__(256) void msdeform_kernel(
    const unsigned short* __restrict__ vproj16, const float* __restrict__ off,
    const float* __restrict__ attnl, const float* __restrict__ refp,
    unsigned short* __restrict__ msout)
{
    __shared__ int4   sIdx[4][8][17];   // [wave][head][point(+pad)]
    __shared__ float4 sWgt[4][8][17];

    const int wave = threadIdx.x >> 6;
    const int lane = threadIdx.x & 63;
    const int bq = blockIdx.x * 4 + wave;
    if (bq >= M_) return;
    const int b = bq / LQ_;
    const int h = lane >> 3;
    const int k = lane & 7;            // handles points p0=2k, p1=2k+1

    // ---- phase 1: weights & indices ----
    const float4 o4  = *reinterpret_cast<const float4*>(off   + (size_t)bq * 256 + h * 32 + 4 * k);
    const float2 lg2 = *reinterpret_cast<const float2*>(attnl + (size_t)bq * 128 + h * 16 + 2 * k);
    const int l = k >> 1;              // level (both points of this lane share it)
    const float2 rp  = *reinterpret_cast<const float2*>(refp  + (size_t)bq * 8 + 2 * l);

    const float Wf[4] = {106.f, 53.f, 27.f, 14.f};
    const float Hf[4] = {76.f, 38.f, 19.f, 10.f};
    const int   Wi[4] = {106, 53, 27, 14};
    const int   Hi[4] = {76, 38, 19, 10};
    const int   St[4] = {0, 8056, 10070, 10583};

    float mx = fmaxf(lg2.x, lg2.y);
    mx = fmaxf(mx, __shfl_xor(mx, 1));
    mx = fmaxf(mx, __shfl_xor(mx, 2));
    mx = fmaxf(mx, __shfl_xor(mx, 4));
    const float e0 = __expf(lg2.x - mx), e1 = __expf(lg2.y - mx);
    float s = e0 + e1;
    s += __shfl_xor(s, 1); s += __shfl_xor(s, 2); s += __shfl_xor(s, 4);
    const float inv = 1.f / s;

    const int W = Wi[l], H = Hi[l];
    const float Wff = Wf[l], Hff = Hf[l];
    const int base = St[l];

    #pragma unroll
    for (int pp = 0; pp < 2; ++pp) {
        const float ox = pp ? o4.z : o4.x;
        const float oy = pp ? o4.w : o4.y;
        const float aw = (pp ? e1 : e0) * inv;
        const float x = fmaf(rp.x, Wff, ox) - 0.5f;
        const float y = fmaf(rp.y, Hff, oy) - 0.5f;
        const float xf = floorf(x), yf = floorf(y);
        const float fx = x - xf, fy = y - yf;
        const int x0 = (int)xf, y0 = (int)yf;
        const float gx = 1.f - fx, gy = 1.f - fy;
        const bool vx0 = (x0 >= 0) && (x0 < W);
        const bool vx1 = (x0 + 1 >= 0) && (x0 + 1 < W);
        const bool vy0 = (y0 >= 0) && (y0 < H);
        const bool vy1 = (y0 + 1 >= 0) && (y0 + 1 < H);
        const int xc0 = min(max(x0, 0), W - 1);
        const int xc1 = min(max(x0 + 1, 0), W - 1);
        const int yr0 = min(max(y0, 0), H - 1) * W;
        const int yr1 = min(max(y0 + 1, 0), H - 1) * W;
        int4 iv;
        float4 wv;
        iv.x = base + yr0 + xc0;  wv.x = (vx0 && vy0) ? gx * gy * aw : 0.f;
        iv.y = base + yr0 + xc1;  wv.y = (vx1 && vy0) ? fx * gy * aw : 0.f;
        iv.z = base + yr1 + xc0;  wv.z = (vx0 && vy1) ? gx * fy * aw : 0.f;
        iv.w = base + yr1 + xc1;  wv.w = (vx1 && vy1) ? fx * fy * aw : 0.f;
        sIdx[wave][h][2 * k + pp] = iv;
        sWgt[wave][h][2 * k + pp] = wv;
    }

    // ---- phase 2: gather + accumulate ----
    // lane -> (h, j): channels j*4 .. j*4+3 of head h  (same h as phase 1)
    const int j = k;
    const unsigned short* vb = vproj16 + (size_t)b * LQ_ * 256 + h * 32 + j * 4;
    float4 acc = make_float4(0.f, 0.f, 0.f, 0.f);
    #pragma unroll
    for (int p = 0; p < 16; ++p) {
        const int4  iv = sIdx[wave][h][p];
        const float4 wv = sWgt[wave][h][p];
        {
            us4 v = *reinterpret_cast<const us4*>(vb + (size_t)iv.x * 256);
            acc.x = fmaf(wv.x, bf2f(v.x), acc.x); acc.y = fmaf(wv.x, bf2f(v.y), acc.y);
            acc.z = fmaf(wv.x, bf2f(v.z), acc.z); acc.w = fmaf(wv.x, bf2f(v.w), acc.w);
        }
        {
            us4 v = *reinterpret_cast<const us4*>(vb + (size_t)iv.y * 256);
            acc.x = fmaf(wv.y, bf2f(v.x), acc.x); acc.y = fmaf(wv.y, bf2f(v.y), acc.y);
            acc.z = fmaf(wv.y, bf2f(v.z), acc.z); acc.w = fmaf(wv.y, bf2f(v.w), acc.w);
        }
        {
            us4 v = *reinterpret_cast<const us4*>(vb + (size_t)iv.z * 256);
            acc.x = fmaf(wv.z, bf2f(v.x), acc.x); acc.y = fmaf(wv.z, bf2f(v.y), acc.y);
            acc.z = fmaf(wv.z, bf2f(v.z), acc.z); acc.w = fmaf(wv.z, bf2f(v.w), acc.w);
        }
        {
            us4 v = *reinterpret_cast<const us4*>(vb + (size_t)iv.w * 256);
            acc.x = fmaf(wv.w, bf2f(v.x), acc.x); acc.y = fmaf(wv.w, bf2f(v.y), acc.y);
            acc.z = fmaf(wv.w, bf2f(v.z), acc.z); acc.w = fmaf(wv.w, bf2f(v.w), acc.w);
        }
    }
    us4 r = { f2bf(acc.x), f2bf(acc.y), f2bf(acc.z), f2bf(acc.w) };
    *reinterpret_cast<us4*>(msout + (size_t)bq * 256 + h * 32 + j * 4) = r;
}

// ---------------------------------------------------------------------------
__global__ __launch_bounds__(256) void add_ln_kernel(
    const float* __restrict__ a, const float* __restrict__ bsrc,
    const float* __restrict__ g, const float* __restrict__ beta,
    float* __restrict__ out, unsigned short* __restrict__ out16)
{
    const int row = blockIdx.x;
    const int c = threadIdx.x;
    const size_t idx = (size_t)row * D_ + c;
    const float x = a[idx] + bsrc[idx];

    __shared__ float red[4];
    const int wid = c >> 6, lane = c & 63;

    float v = x;
    #pragma unroll
    for (int o = 32; o > 0; o >>= 1) v += __shfl_down(v, o, 64);
    if (lane == 0) red[wid] = v;
    __syncthreads();
    const float mean = (red[0] + red[1] + red[2] + red[3]) * (1.f / 256.f);
    const float dx = x - mean;

    float v2 = dx * dx;
    #pragma unroll
    for (int o = 32; o > 0; o >>= 1) v2 += __shfl_down(v2, o, 64);
    __syncthreads();
    if (lane == 0) red[wid] = v2;
    __syncthreads();
    const float var = (red[0] + red[1] + red[2] + red[3]) * (1.f / 256.f);

    const float y = dx * rsqrtf(var + 1e-5f) * g[c] + beta[c];
    out[idx] = y;
    if (out16) out16[idx] = f2bf(y);
}

// ---------------------------------------------------------------------------
extern "C" void kernel_launch(void* const* d_in, const int* in_sizes, int n_in,
                              void* d_out, int out_size, void* d_ws, size_t ws_size,
                              hipStream_t stream) {
    const float* query = (const float*)d_in[0];
    const float* qpos  = (const float*)d_in[1];
    const float* value = (const float*)d_in[2];
    const float* refp  = (const float*)d_in[3];
    const float* W_off  = (const float*)d_in[6];
    const float* b_off  = (const float*)d_in[7];
    const float* W_attn = (const float*)d_in[8];
    const float* b_attn = (const float*)d_in[9];
    const float* W_v    = (const float*)d_in[10];
    const float* b_v    = (const float*)d_in[11];
    const float* W_out  = (const float*)d_in[12];
    const float* b_out  = (const float*)d_in[13];
    const float* ln1_g  = (const float*)d_in[14];
    const float* ln1_b  = (const float*)d_in[15];
    const float* W1     = (const float*)d_in[16];
    const float* b1     = (const float*)d_in[17];
    const float* W2     = (const float*)d_in[18];
    const float* b2     = (const float*)d_in[19];
    const float* ln2_g  = (const float*)d_in[20];
    const float* ln2_b  = (const float*)d_in[21];
    float* out = (float*)d_out;

    // ---- workspace layout ----
    uint8_t* w = (uint8_t*)d_ws;
    unsigned short* WvT   = (unsigned short*)(w);
    unsigned short* WoffT = WvT    + 65536;
    unsigned short* WattnT= WoffT  + 65536;
    unsigned short* WoutT = WattnT + 32768;
    unsigned short* W1T   = WoutT  + 65536;
    unsigned short* W2T   = W1T    + 262144;
    uint8_t* base = (uint8_t*)(W2T + 262144);
    base = (uint8_t*)(((uintptr_t)base + 255) & ~(uintptr_t)255);

    const size_t A = (size_t)M_ * D_;
    unsigned short* R_v16  = (unsigned short*)base;          // v16  -> q1b16
    unsigned short* R_q16  = R_v16 + A;                      // qb16 -> ms16
    unsigned short* R_vp16 = R_q16 + A;                      // vproj bf16
    float* R_off   = (float*)(R_vp16 + A);                   // off -> src2 -> ffn
    float* R_attnl = R_off + A;                              // attn logits (M,128)
    float* R_q1    = R_attnl + A / 2;                        // q1 f32
    unsigned short* R_h16 = (unsigned short*)(R_q1 + A);     // FFN hidden bf16 (M,1024)

    const dim3 blk(256);
    auto cdiv = [](size_t a, size_t b) { return (unsigned)((a + b - 1) / b); };

    transpose_bf16_kernel<<<cdiv(256 * 256, 256), blk, 0, stream>>>(W_v,    WvT,    256, 256);
    transpose_bf16_kernel<<<cdiv(256 * 256, 256), blk, 0, stream>>>(W_off,  WoffT,  256, 256);
    transpose_bf16_kernel<<<cdiv(256 * 128, 256), blk, 0, stream>>>(W_attn, WattnT, 256, 128);
    transpose_bf16_kernel<<<cdiv(256 * 256, 256), blk, 0, stream>>>(W_out,  WoutT,  256, 256);
    transpose_bf16_kernel<<<cdiv(256 * 1024, 256), blk, 0, stream>>>(W1,    W1T,    256, 1024);
    transpose_bf16_kernel<<<cdiv(1024 * 256, 256), blk, 0, stream>>>(W2,    W2T,    1024, 256);

    f32_to_bf16_kernel<<<cdiv(A / 4, 256), blk, 0, stream>>>(value, R_v16, A / 4);
    add_q_kernel<<<cdiv(A / 4, 256), blk, 0, stream>>>(query, qpos, R_q16, A / 4);

    const unsigned MT = (M_ + 127) / 128;   // 168
    // vproj (bf16 out for the gather)
    gemm_mfma<0, 1><<<dim3(2, MT), blk, 0, stream>>>(R_v16, WvT, b_v, R_vp16, M_, 256, 256);
    // off (f32)
    gemm_mfma<0, 0><<<dim3(2, MT), blk, 0, stream>>>(R_q16, WoffT, b_off, R_off, M_, 256, 256);
    // attn logits (f32)
    gemm_mfma<0, 0><<<dim3(1, MT), blk, 0, stream>>>(R_q16, WattnT, b_attn, R_attnl, M_, 128, 256);
    // deformable attention -> ms16 (overwrites R_q16, dead)
    msdeform_kernel<<<dim3(cdiv(M_, 4)), blk, 0, stream>>>(R_vp16, R_off, R_attnl, refp, R_q16);
    // src2 = ms16 @ WoutT^T (f32) -> reuse R_off (dead)
    gemm_mfma<0, 0><<<dim3(2, MT), blk, 0, stream>>>(R_q16, WoutT, b_out, R_off, M_, 256, 256);
    // q1 = LN(query + src2): f32 -> R_q1, bf16 -> R_v16 (dead)
    add_ln_kernel<<<dim3(M_), blk, 0, stream>>>(query, R_off, ln1_g, ln1_b, R_q1, R_v16);
    // h = relu(q1b @ W1T^T) bf16
    gemm_mfma<1, 1><<<dim3(8, MT), blk, 0, stream>>>(R_v16, W1T, b1, R_h16, M_, 1024, 256);
    // ffn = h @ W2T^T (f32) -> reuse R_off
    gemm_mfma<0, 0><<<dim3(2, MT), blk, 0, stream>>>(R_h16, W2T, b2, R_off, M_, 256, 1024);
    // out = LN(q1 + ffn)
    add_ln_kernel<<<dim3(M_), blk, 0, stream>>>(R_q1, R_off, ln2_g, ln2_b, out, nullptr);
}

// Round 4
// 215.224 us; speedup vs baseline: 3.8523x; 1.2505x over previous
//
#include <hip/hip_runtime.h>
#include <math.h>

#define B_   2
#define LQ_  10723
#define D_   256
#define NH_  8
#define HD_  32
#define NL_  4
#define NP_  4
#define DFF_ 1024
#define M_   (B_ * LQ_)   // 21446

typedef __attribute__((ext_vector_type(4))) float f32x4;
typedef __attribute__((ext_vector_type(8))) short short8;
typedef __attribute__((ext_vector_type(4))) unsigned short us4;

__device__ __forceinline__ unsigned short f2bf(float f) {
    union { float f; unsigned int u; } x; x.f = f;
    unsigned int r = x.u + 0x7FFF + ((x.u >> 16) & 1);   // RNE
    return (unsigned short)(r >> 16);
}
__device__ __forceinline__ float bf2f(unsigned short u) {
    union { unsigned int u; float f; } x; x.u = (unsigned int)u << 16;
    return x.f;
}

#define AS3U(p) ((__attribute__((address_space(3))) unsigned int*)(uintptr_t)(p))
#define AS1U(p) ((const __attribute__((address_space(1))) unsigned int*)(uintptr_t)(p))

// ---------------------------------------------------------------------------
// One-shot weight prep: f32 (K,N) -> bf16 (N,K); off+attn fused into WoaT.
// Region sizes (dst elems): WvT 65536 | WoaT 98304 | WoutT 65536 | W1T 262144 | W2T 262144
// ---------------------------------------------------------------------------
__global__ __launch_bounds__(256) void prep_weights_kernel(
    const float* __restrict__ Wv, const float* __restrict__ Woff,
    const float* __restrict__ Wattn, const float* __restrict__ Wout,
    const float* __restrict__ W1, const float* __restrict__ W2,
    unsigned short* __restrict__ WvT, unsigned short* __restrict__ WoaT,
    unsigned short* __restrict__ WoutT, unsigned short* __restrict__ W1T,
    unsigned short* __restrict__ W2T)
{
    int idx = blockIdx.x * 256 + threadIdx.x;
    if (idx < 65536) {
        int n = idx >> 8, k = idx & 255;
        WvT[idx] = f2bf(Wv[k * 256 + n]);
    } else if (idx < 163840) {
        int l = idx - 65536; int n = l >> 8, k = l & 255;
        WoaT[l] = f2bf(n < 256 ? Woff[k * 256 + n] : Wattn[k * 128 + (n - 256)]);
    } else if (idx < 229376) {
        int l = idx - 163840; int n = l >> 8, k = l & 255;
        WoutT[l] = f2bf(Wout[k * 256 + n]);
    } else if (idx < 491520) {
        int l = idx - 229376; int n = l >> 8, k = l & 255;
        W1T[l] = f2bf(W1[k * 1024 + n]);
    } else if (idx < 753664) {
        int l = idx - 491520; int n = l >> 10, k = l & 1023;
        W2T[l] = f2bf(W2[k * 256 + n]);
    }
}

// value -> bf16  and  q = bf16(query + qpos), one kernel. n4 = A/4 per half.
__global__ __launch_bounds__(256) void prep_acts_kernel(
    const float* __restrict__ value, const float* __restrict__ query,
    const float* __restrict__ qpos,
    unsigned short* __restrict__ v16, unsigned short* __restrict__ q16, size_t n4)
{
    size_t i = (size_t)blockIdx.x * 256 + threadIdx.x;
    if (i < n4) {
        float4 v = reinterpret_cast<const float4*>(value)[i];
        us4 r = { f2bf(v.x), f2bf(v.y), f2bf(v.z), f2bf(v.w) };
        reinterpret_cast<us4*>(v16)[i] = r;
    } else if (i < 2 * n4) {
        size_t j = i - n4;
        float4 va = reinterpret_cast<const float4*>(query)[j];
        float4 vb = reinterpret_cast<const float4*>(qpos)[j];
        us4 r = { f2bf(va.x + vb.x), f2bf(va.y + vb.y), f2bf(va.z + vb.z), f2bf(va.w + vb.w) };
        reinterpret_cast<us4*>(q16)[j] = r;
    }
}

// ---------------------------------------------------------------------------
// MFMA bf16 GEMM: C[M,N] = A[M,K] @ BT[N,K]^T + bias[N]   (m97 structure)
// ---------------------------------------------------------------------------
template<int RELU, int OUT_BF16>
__global__ __launch_bounds__(256) void gemm_mfma(
    const unsigned short* __restrict__ A,
    const unsigned short* __restrict__ BT,
    const float* __restrict__ bias,
    void* __restrict__ Cout,
    int M, int N, int K)
{
    __shared__ unsigned short As[128 * 32];
    __shared__ unsigned short Bs[128 * 32];

    const int tid  = threadIdx.x;
    const int wave = tid >> 6;
    const int lane = tid & 63;
    const int m0 = blockIdx.y * 128;
    const int n0 = blockIdx.x * 128;
    const int wr = (wave >> 1) * 64;
    const int wc = (wave & 1) * 64;

    f32x4 acc[4][4] = {};
    const int soff = wave * 1024 + lane * 16;

    for (int k0 = 0; k0 < K; k0 += 32) {
        __syncthreads();
        #pragma unroll
        for (int p = 0; p < 2; ++p) {
            const int off  = p * 4096 + soff;
            const int row  = off >> 6;
            const int colb = off & 63;
            int ar = m0 + row; ar = (ar < M) ? ar : (M - 1);
            __builtin_amdgcn_global_load_lds(AS1U(A + (size_t)ar * K + k0 + (colb >> 1)),
                AS3U(As + ((p * 4096 + wave * 1024) >> 1)), 16, 0, 0);
            __builtin_amdgcn_global_load_lds(AS1U(BT + (size_t)(n0 + row) * K + k0 + (colb >> 1)),
                AS3U(Bs + ((p * 4096 + wave * 1024) >> 1)), 16, 0, 0);
        }
        __syncthreads();

        const int fr = lane & 15;
        const int kb = (lane >> 4) * 8;
        short8 af[4], bf[4];
        #pragma unroll
        for (int m = 0; m < 4; ++m)
            af[m] = *reinterpret_cast<const short8*>(As + (wr + m * 16 + fr) * 32 + kb);
        #pragma unroll
        for (int n = 0; n < 4; ++n)
            bf[n] = *reinterpret_cast<const short8*>(Bs + (wc + n * 16 + fr) * 32 + kb);
        #pragma unroll
        for (int m = 0; m < 4; ++m)
            #pragma unroll
            for (int n = 0; n < 4; ++n)
                acc[m][n] = __builtin_amdgcn_mfma_f32_16x16x32_bf16(af[m], bf[n], acc[m][n], 0, 0, 0);
    }

    const int fr = lane & 15;
    const int r0 = (lane >> 4) * 4;
    #pragma unroll
    for (int n = 0; n < 4; ++n) {
        const int col = n0 + wc + n * 16 + fr;
        const float bv = bias[col];
        #pragma unroll
        for (int m = 0; m < 4; ++m) {
            #pragma unroll
            for (int r = 0; r < 4; ++r) {
                const int row = m0 + wr + m * 16 + r0 + r;
                if (row < M) {
                    float v = acc[m][n][r] + bv;
                    if (RELU) v = fmaxf(v, 0.f);
                    if (OUT_BF16)
                        ((unsigned short*)Cout)[(size_t)row * N + col] = f2bf(v);
                    else
                        ((float*)Cout)[(size_t)row * N + col] = v;
                }
            }
        }
    }
}

// ---------------------------------------------------------------------------
// GEMM (N=256 fixed) + bias + residual + LayerNorm, fused.
// BM=128, BN=256, BK=32, 512 threads = 8 waves (2 row x 4 col).
// outf = LN(res + A@BT^T + bias) * g + beta;  out16 optional bf16 mirror.
// ---------------------------------------------------------------------------
template<int MIRROR>
__global__ __launch_bounds__(512) void gemm_ln(
    const unsigned short* __restrict__ A,
    const unsigned short* __restrict__ BT,
    const float* __restrict__ bias,
    const float* __restrict__ res,
    const float* __restrict__ g,
    const float* __restrict__ beta,
    float* __restrict__ outf,
    unsigned short* __restrict__ out16,
    int M, int K)
{
    __shared__ unsigned short As[128 * 32];
    __shared__ unsigned short Bs[256 * 32];
    __shared__ float2 sRed[4][128];

    const int tid  = threadIdx.x;
    const int wave = tid >> 6;
    const int lane = tid & 63;
    const int m0 = blockIdx.x * 128;
    const int wr = (wave >> 2) * 64;
    const int wc = (wave & 3) * 64;

    f32x4 acc[4][4] = {};

    for (int k0 = 0; k0 < K; k0 += 32) {
        __syncthreads();
        {   // A tile: 8192 B, one pass (512 thr x 16 B)
            const int off  = tid * 16;
            const int row  = off >> 6;
            const int colb = off & 63;
            int ar = m0 + row; ar = (ar < M) ? ar : (M - 1);
            __builtin_amdgcn_global_load_lds(AS1U(A + (size_t)ar * K + k0 + (colb >> 1)),
                AS3U(As + (off >> 1)), 16, 0, 0);
        }
        #pragma unroll
        for (int p = 0; p < 2; ++p) {   // B tile: 16384 B, two passes
            const int off  = p * 8192 + tid * 16;
            const int row  = off >> 6;
            const int colb = off & 63;
            __builtin_amdgcn_global_load_lds(AS1U(BT + (size_t)row * K + k0 + (colb >> 1)),
                AS3U(Bs + (off >> 1)), 16, 0, 0);
        }
        __syncthreads();

        const int fr = lane & 15;
        const int kb = (lane >> 4) * 8;
        short8 af[4], bf[4];
        #pragma unroll
        for (int m = 0; m < 4; ++m)
            af[m] = *reinterpret_cast<const short8*>(As + (wr + m * 16 + fr) * 32 + kb);
        #pragma unroll
        for (int n = 0; n < 4; ++n)
            bf[n] = *reinterpret_cast<const short8*>(Bs + (wc + n * 16 + fr) * 32 + kb);
        #pragma unroll
        for (int m = 0; m < 4; ++m)
            #pragma unroll
            for (int n = 0; n < 4; ++n)
                acc[m][n] = __builtin_amdgcn_mfma_f32_16x16x32_bf16(af[m], bf[n], acc[m][n], 0, 0, 0);
    }

    // ---- epilogue: bias + residual, then row-LN over 256 cols ----
    const int fr = lane & 15;
    const int r0 = (lane >> 4) * 4;
    float biasv[4], gv[4], bev[4];
    #pragma unroll
    for (int n = 0; n < 4; ++n) {
        const int col = wc + n * 16 + fr;
        biasv[n] = bias[col]; gv[n] = g[col]; bev[n] = beta[col];
    }
    // acc <- value (bias + residual added)
    #pragma unroll
    for (int m = 0; m < 4; ++m) {
        #pragma unroll
        for (int r = 0; r < 4; ++r) {
            int row = m0 + wr + m * 16 + r0 + r;
            int rr = (row < M) ? row : (M - 1);
            const float* rp = res + (size_t)rr * 256;
            #pragma unroll
            for (int n = 0; n < 4; ++n)
                acc[m][n][r] += biasv[n] + rp[wc + n * 16 + fr];
        }
    }
    // per-row {sum, sumsq}: reduce over n (local), then over fr lanes, then col-waves
    #pragma unroll
    for (int m = 0; m < 4; ++m) {
        #pragma unroll
        for (int r = 0; r < 4; ++r) {
            float sx = 0.f, sxx = 0.f;
            #pragma unroll
            for (int n = 0; n < 4; ++n) { float t = acc[m][n][r]; sx += t; sxx += t * t; }
            #pragma unroll
            for (int mask = 1; mask < 16; mask <<= 1) {
                sx  += __shfl_xor(sx, mask);
                sxx += __shfl_xor(sxx, mask);
            }
            if (fr == 0) sRed[wave & 3][wr + m * 16 + r0 + r] = make_float2(sx, sxx);
        }
    }
    __syncthreads();
    #pragma unroll
    for (int m = 0; m < 4; ++m) {
        #pragma unroll
        for (int r = 0; r < 4; ++r) {
            const int lr = wr + m * 16 + r0 + r;
            float2 a0 = sRed[0][lr], a1 = sRed[1][lr], a2 = sRed[2][lr], a3 = sRed[3][lr];
            const float S  = a0.x + a1.x + a2.x + a3.x;
            const float SS = a0.y + a1.y + a2.y + a3.y;
            const float mean = S * (1.f / 256.f);
            const float var  = SS * (1.f / 256.f) - mean * mean;
            const float rstd = rsqrtf(var + 1e-5f);
            const int row = m0 + lr;
            if (row < M) {
                #pragma unroll
                for (int n = 0; n < 4; ++n) {
                    const int col = wc + n * 16 + fr;
                    const float y = (acc[m][n][r] - mean) * rstd * gv[n] + bev[n];
                    outf[(size_t)row * 256 + col] = y;
                    if (MIRROR) out16[(size_t)row * 256 + col] = f2bf(y);
                }
            }
        }
    }
}

// ---------------------------------------------------------------------------
// Multi-scale deformable attention: one wave per query (4 / block).
// offattn: (M, 384) = [off(256) | attn logits(128)] fused GEMM output.
// ---------------------------------------------------------------------------
__global__ __launch_bounds__(256) void msdeform_kernel(
    const unsigned short* __restrict__ vproj16, const float* __restrict__ offattn,
    const float* __restrict__ refp, unsigned short* __restrict__ msout)
{
    __shared__ int4   sIdx[4][8][17];
    __shared__ float4 sWgt[4][8][17];

    const int wave = threadIdx.x >> 6;
    const int lane = threadIdx.x & 63;
    const int bq = blockIdx.x * 4 + wave;
    if (bq >= M_) return;
    const int b = bq / LQ_;
    const int h = lane >> 3;
    const int k = lane & 7;

    const float4 o4  = *reinterpret_cast<const float4*>(offattn + (size_t)bq * 384 + h * 32 + 4 * k);
    const float2 lg2 = *reinterpret_cast<const float2*>(offattn + (size_t)bq * 384 + 256 + h * 16 + 2 * k);
    const int l = k >> 1;
    const float2 rp  = *reinterpret_cast<const float2*>(refp + (size_t)bq * 8 + 2 * l);

    const float Wf[4] = {106.f, 53.f, 27.f, 14.f};
    const float Hf[4] = {76.f, 38.f, 19.f, 10.f};
    const int   Wi[4] = {106, 53, 27, 14};
    const int   Hi[4] = {76, 38, 19, 10};
    const int   St[4] = {0, 8056, 10070, 10583};

    float mx = fmaxf(lg2.x, lg2.y);
    mx = fmaxf(mx, __shfl_xor(mx, 1));
    mx = fmaxf(mx, __shfl_xor(mx, 2));
    mx = fmaxf(mx, __shfl_xor(mx, 4));
    const float e0 = __expf(lg2.x - mx), e1 = __expf(lg2.y - mx);
    float s = e0 + e1;
    s += __shfl_xor(s, 1); s += __shfl_xor(s, 2); s += __shfl_xor(s, 4);
    const float inv = 1.f / s;

    const int W = Wi[l], H = Hi[l];
    const float Wff = Wf[l], Hff = Hf[l];
    const int base = St[l];

    #pragma unroll
    for (int pp = 0; pp < 2; ++pp) {
        const float ox = pp ? o4.z : o4.x;
        const float oy = pp ? o4.w : o4.y;
        const float aw = (pp ? e1 : e0) * inv;
        const float x = fmaf(rp.x, Wff, ox) - 0.5f;
        const float y = fmaf(rp.y, Hff, oy) - 0.5f;
        const float xf = floorf(x), yf = floorf(y);
        const float fx = x - xf, fy = y - yf;
        const int x0 = (int)xf, y0 = (int)yf;
        const float gx = 1.f - fx, gy = 1.f - fy;
        const bool vx0 = (x0 >= 0) && (x0 < W);
        const bool vx1 = (x0 + 1 >= 0) && (x0 + 1 < W);
        const bool vy0 = (y0 >= 0) && (y0 < H);
        const bool vy1 = (y0 + 1 >= 0) && (y0 + 1 < H);
        const int xc0 = min(max(x0, 0), W - 1);
        const int xc1 = min(max(x0 + 1, 0), W - 1);
        const int yr0 = min(max(y0, 0), H - 1) * W;
        const int yr1 = min(max(y0 + 1, 0), H - 1) * W;
        int4 iv; float4 wv;
        iv.x = base + yr0 + xc0;  wv.x = (vx0 && vy0) ? gx * gy * aw : 0.f;
        iv.y = base + yr0 + xc1;  wv.y = (vx1 && vy0) ? fx * gy * aw : 0.f;
        iv.z = base + yr1 + xc0;  wv.z = (vx0 && vy1) ? gx * fy * aw : 0.f;
        iv.w = base + yr1 + xc1;  wv.w = (vx1 && vy1) ? fx * fy * aw : 0.f;
        sIdx[wave][h][2 * k + pp] = iv;
        sWgt[wave][h][2 * k + pp] = wv;
    }

    const int j = k;
    const unsigned short* vb = vproj16 + (size_t)b * LQ_ * 256 + h * 32 + j * 4;
    float4 acc = make_float4(0.f, 0.f, 0.f, 0.f);
    #pragma unroll
    for (int p = 0; p < 16; ++p) {
        const int4  iv = sIdx[wave][h][p];
        const float4 wv = sWgt[wave][h][p];
        {
            us4 v = *reinterpret_cast<const us4*>(vb + (size_t)iv.x * 256);
            acc.x = fmaf(wv.x, bf2f(v.x), acc.x); acc.y = fmaf(wv.x, bf2f(v.y), acc.y);
            acc.z = fmaf(wv.x, bf2f(v.z), acc.z); acc.w = fmaf(wv.x, bf2f(v.w), acc.w);
        }
        {
            us4 v = *reinterpret_cast<const us4*>(vb + (size_t)iv.y * 256);
            acc.x = fmaf(wv.y, bf2f(v.x), acc.x); acc.y = fmaf(wv.y, bf2f(v.y), acc.y);
            acc.z = fmaf(wv.y, bf2f(v.z), acc.z); acc.w = fmaf(wv.y, bf2f(v.w), acc.w);
        }
        {
            us4 v = *reinterpret_cast<const us4*>(vb + (size_t)iv.z * 256);
            acc.x = fmaf(wv.z, bf2f(v.x), acc.x); acc.y = fmaf(wv.z, bf2f(v.y), acc.y);
            acc.z = fmaf(wv.z, bf2f(v.z), acc.z); acc.w = fmaf(wv.z, bf2f(v.w), acc.w);
        }
        {
            us4 v = *reinterpret_cast<const us4*>(vb + (size_t)iv.w * 256);
            acc.x = fmaf(wv.w, bf2f(v.x), acc.x); acc.y = fmaf(wv.w, bf2f(v.y), acc.y);
            acc.z = fmaf(wv.w, bf2f(v.z), acc.z); acc.w = fmaf(wv.w, bf2f(v.w), acc.w);
        }
    }
    us4 r = { f2bf(acc.x), f2bf(acc.y), f2bf(acc.z), f2bf(acc.w) };
    *reinterpret_cast<us4*>(msout + (size_t)bq * 256 + h * 32 + j * 4) = r;
}

// ---------------------------------------------------------------------------
extern "C" void kernel_launch(void* const* d_in, const int* in_sizes, int n_in,
                              void* d_out, int out_size, void* d_ws, size_t ws_size,
                              hipStream_t stream) {
    const float* query = (const float*)d_in[0];
    const float* qpos  = (const float*)d_in[1];
    const float* value = (const float*)d_in[2];
    const float* refp  = (const float*)d_in[3];
    const float* W_off  = (const float*)d_in[6];
    const float* b_off  = (const float*)d_in[7];
    const float* W_attn = (const float*)d_in[8];
    const float* b_attn = (const float*)d_in[9];
    const float* W_v    = (const float*)d_in[10];
    const float* b_v    = (const float*)d_in[11];
    const float* W_out  = (const float*)d_in[12];
    const float* b_out  = (const float*)d_in[13];
    const float* ln1_g  = (const float*)d_in[14];
    const float* ln1_b  = (const float*)d_in[15];
    const float* W1     = (const float*)d_in[16];
    const float* b1     = (const float*)d_in[17];
    const float* W2     = (const float*)d_in[18];
    const float* b2     = (const float*)d_in[19];
    const float* ln2_g  = (const float*)d_in[20];
    const float* ln2_b  = (const float*)d_in[21];
    float* out = (float*)d_out;

    // ---- workspace layout ----
    unsigned short* WvT   = (unsigned short*)d_ws;
    unsigned short* WoaT  = WvT   + 65536;    // 384 x 256  (off | attn)
    unsigned short* WoutT = WoaT  + 98304;
    unsigned short* W1T   = WoutT + 65536;    // 1024 x 256
    unsigned short* W2T   = W1T   + 262144;   // 256 x 1024
    uint8_t* base = (uint8_t*)(W2T + 262144);
    base = (uint8_t*)(((uintptr_t)base + 255) & ~(uintptr_t)255);

    const size_t A = (size_t)M_ * D_;
    unsigned short* R_v16  = (unsigned short*)base;          // value bf16 -> q1 bf16 mirror
    unsigned short* R_q16  = R_v16 + A;                      // q bf16 -> ms16
    unsigned short* R_vp16 = R_q16 + A;                      // vproj bf16
    float* R_oa  = (float*)(R_vp16 + A);                     // off|attn (M,384)
    float* R_q1  = R_oa + (size_t)M_ * 384;                  // q1 f32
    unsigned short* R_h16 = (unsigned short*)(R_q1 + A);     // FFN hidden bf16 (M,1024)

    const dim3 blk(256);
    auto cdiv = [](size_t a, size_t b) { return (unsigned)((a + b - 1) / b); };

    prep_weights_kernel<<<cdiv(753664, 256), blk, 0, stream>>>(
        W_v, W_off, W_attn, W_out, W1, W2, WvT, WoaT, WoutT, W1T, W2T);
    prep_acts_kernel<<<cdiv(2 * (A / 4), 256), blk, 0, stream>>>(
        value, query, qpos, R_v16, R_q16, A / 4);

    const unsigned MT = (M_ + 127) / 128;   // 168
    // vproj (bf16 out for the gather)
    gemm_mfma<0, 1><<<dim3(2, MT), blk, 0, stream>>>(R_v16, WvT, b_v, R_vp16, M_, 256, 256);
    // off|attn fused (f32, N=384). bias: concat b_off|b_attn -> need combined bias.
    // b_off is 256, b_attn is 128; pass via small on-the-fly trick: write combined into R_oa head? 
    // Simpler: bias pointer arithmetic inside GEMM requires contiguity; build it in prep_weights?
    // We use a dedicated tiny buffer appended after W2T region inside prep (see below).
    {
        // combined bias lives right after R_h16
        float* b_oa = (float*)(R_h16 + (size_t)M_ * 1024);
        // fill with a tiny kernel-free approach: reuse prep_acts? Use a micro kernel:
        // (declared below via lambda-style launch)
        extern __global__ void concat_bias_kernel(const float*, const float*, float*);
        concat_bias_kernel<<<dim3(2), dim3(256), 0, stream>>>(b_off, b_attn, b_oa);
        gemm_mfma<0, 0><<<dim3(3, MT), blk, 0, stream>>>(R_q16, WoaT, b_oa, R_oa, M_, 384, 256);
    }
    // deformable attention -> ms16 (overwrites R_q16, dead)
    msdeform_kernel<<<dim3(cdiv(M_, 4)), blk, 0, stream>>>(R_vp16, R_oa, refp, R_q16);
    // q1 = LN(query + ms16@WoutT^T + b_out): f32 -> R_q1, bf16 -> R_v16 (dead)
    gemm_ln<1><<<dim3(MT), dim3(512), 0, stream>>>(
        R_q16, WoutT, b_out, query, ln1_g, ln1_b, R_q1, R_v16, M_, 256);
    // h = relu(q1b @ W1T^T) bf16
    gemm_mfma<1, 1><<<dim3(8, MT), blk, 0, stream>>>(R_v16, W1T, b1, R_h16, M_, 1024, 256);
    // out = LN(q1 + h@W2T^T + b2)
    gemm_ln<0><<<dim3(MT), dim3(512), 0, stream>>>(
        R_h16, W2T, b2, R_q1, ln2_g, ln2_b, out, nullptr, M_, 1024);
}

// combined bias for the fused off|attn GEMM: [b_off(256) | b_attn(128)]
__global__ __launch_bounds__(256) void concat_bias_kernel(
    const float* __restrict__ b_off, const float* __restrict__ b_attn,
    float* __restrict__ dst)
{
    int i = blockIdx.x * 256 + threadIdx.x;
    if (i < 256) dst[i] = b_off[i];
    else if (i < 384) dst[i] = b_attn[i - 256];
}

// Round 5
// 201.782 us; speedup vs baseline: 4.1089x; 1.0666x over previous
//
#include <hip/hip_runtime.h>
#include <math.h>

#define B_   2
#define LQ_  10723
#define D_   256
#define NH_  8
#define HD_  32
#define NL_  4
#define NP_  4
#define DFF_ 1024
#define M_   (B_ * LQ_)   // 21446

typedef __attribute__((ext_vector_type(4))) float f32x4;
typedef __attribute__((ext_vector_type(8))) short short8;
typedef __attribute__((ext_vector_type(4))) unsigned short us4;

__device__ __forceinline__ unsigned short f2bf(float f) {
    union { float f; unsigned int u; } x; x.f = f;
    unsigned int r = x.u + 0x7FFF + ((x.u >> 16) & 1);   // RNE
    return (unsigned short)(r >> 16);
}

#define AS3U(p) ((__attribute__((address_space(3))) unsigned int*)(uintptr_t)(p))
#define AS1U(p) ((const __attribute__((address_space(1))) unsigned int*)(uintptr_t)(p))

// ---------------------------------------------------------------------------
// One-shot weight prep: f32 (K,N) -> bf16 (N,K); off|attn fused; b_oa concat.
// ---------------------------------------------------------------------------
__global__ __launch_bounds__(256) void prep_weights_kernel(
    const float* __restrict__ Wv, const float* __restrict__ Woff,
    const float* __restrict__ Wattn, const float* __restrict__ Wout,
    const float* __restrict__ W1, const float* __restrict__ W2,
    const float* __restrict__ b_off, const float* __restrict__ b_attn,
    unsigned short* __restrict__ WvT, unsigned short* __restrict__ WoaT,
    unsigned short* __restrict__ WoutT, unsigned short* __restrict__ W1T,
    unsigned short* __restrict__ W2T, float* __restrict__ b_oa)
{
    int idx = blockIdx.x * 256 + threadIdx.x;
    if (idx < 65536) {
        int n = idx >> 8, k = idx & 255;
        WvT[idx] = f2bf(Wv[k * 256 + n]);
    } else if (idx < 163840) {
        int l = idx - 65536; int n = l >> 8, k = l & 255;
        WoaT[l] = f2bf(n < 256 ? Woff[k * 256 + n] : Wattn[k * 128 + (n - 256)]);
    } else if (idx < 229376) {
        int l = idx - 163840; int n = l >> 8, k = l & 255;
        WoutT[l] = f2bf(Wout[k * 256 + n]);
    } else if (idx < 491520) {
        int l = idx - 229376; int n = l >> 8, k = l & 255;
        W1T[l] = f2bf(W1[k * 1024 + n]);
    } else if (idx < 753664) {
        int l = idx - 491520; int n = l >> 10, k = l & 1023;
        W2T[l] = f2bf(W2[k * 256 + n]);
    } else if (idx < 754048) {
        int l = idx - 753664;
        b_oa[l] = (l < 256) ? b_off[l] : b_attn[l - 256];
    }
}

// value -> bf16  and  q = bf16(query + qpos)
__global__ __launch_bounds__(256) void prep_acts_kernel(
    const float* __restrict__ value, const float* __restrict__ query,
    const float* __restrict__ qpos,
    unsigned short* __restrict__ v16, unsigned short* __restrict__ q16, size_t n4)
{
    size_t i = (size_t)blockIdx.x * 256 + threadIdx.x;
    if (i < n4) {
        float4 v = reinterpret_cast<const float4*>(value)[i];
        us4 r = { f2bf(v.x), f2bf(v.y), f2bf(v.z), f2bf(v.w) };
        reinterpret_cast<us4*>(v16)[i] = r;
    } else if (i < 2 * n4) {
        size_t j = i - n4;
        float4 va = reinterpret_cast<const float4*>(query)[j];
        float4 vb = reinterpret_cast<const float4*>(qpos)[j];
        us4 r = { f2bf(va.x + vb.x), f2bf(va.y + vb.y), f2bf(va.z + vb.z), f2bf(va.w + vb.w) };
        reinterpret_cast<us4*>(q16)[j] = r;
    }
}

// ---------------------------------------------------------------------------
// MFMA bf16 GEMM, 2-phase double-buffered (T3-minimum):
// C[M,N] = A[M,K] @ BT[N,K]^T + bias[N].  128x128 tile, BK=32, 4 waves.
// ---------------------------------------------------------------------------
template<int RELU, int OUT_BF16>
__global__ __launch_bounds__(256) void gemm_mfma(
    const unsigned short* __restrict__ A,
    const unsigned short* __restrict__ BT,
    const float* __restrict__ bias,
    void* __restrict__ Cout,
    int M, int N, int K)
{
    __shared__ unsigned short As[2][128 * 32];
    __shared__ unsigned short Bs[2][128 * 32];

    const int tid  = threadIdx.x;
    const int wave = tid >> 6;
    const int lane = tid & 63;
    const int m0 = blockIdx.y * 128;
    const int n0 = blockIdx.x * 128;
    const int wr = (wave >> 1) * 64;
    const int wc = (wave & 1) * 64;

    f32x4 acc[4][4] = {};
    const int soff = wave * 1024 + lane * 16;

    auto stage = [&](int buf, int k0) {
        #pragma unroll
        for (int p = 0; p < 2; ++p) {
            const int off  = p * 4096 + soff;
            const int row  = off >> 6;
            const int colb = off & 63;
            int ar = m0 + row; ar = (ar < M) ? ar : (M - 1);
            __builtin_amdgcn_global_load_lds(AS1U(A + (size_t)ar * K + k0 + (colb >> 1)),
                AS3U(&As[buf][(p * 4096 + wave * 1024) >> 1]), 16, 0, 0);
            __builtin_amdgcn_global_load_lds(AS1U(BT + (size_t)(n0 + row) * K + k0 + (colb >> 1)),
                AS3U(&Bs[buf][(p * 4096 + wave * 1024) >> 1]), 16, 0, 0);
        }
    };

    const int nt = K >> 5;
    stage(0, 0);
    __syncthreads();                 // prologue: tile 0 resident
    int cur = 0;
    for (int t = 0; t < nt; ++t) {
        if (t + 1 < nt) stage(cur ^ 1, (t + 1) * 32);   // prefetch overlaps compute

        const int fr = lane & 15;
        const int kb = (lane >> 4) * 8;
        short8 af[4], bf[4];
        #pragma unroll
        for (int m = 0; m < 4; ++m)
            af[m] = *reinterpret_cast<const short8*>(&As[cur][(wr + m * 16 + fr) * 32 + kb]);
        #pragma unroll
        for (int n = 0; n < 4; ++n)
            bf[n] = *reinterpret_cast<const short8*>(&Bs[cur][(wc + n * 16 + fr) * 32 + kb]);
        #pragma unroll
        for (int m = 0; m < 4; ++m)
            #pragma unroll
            for (int n = 0; n < 4; ++n)
                acc[m][n] = __builtin_amdgcn_mfma_f32_16x16x32_bf16(af[m], bf[n], acc[m][n], 0, 0, 0);

        if (t + 1 < nt) { __syncthreads(); cur ^= 1; }  // drains prefetch (vmcnt0+lgkm0)
    }

    const int fr = lane & 15;
    const int r0 = (lane >> 4) * 4;
    #pragma unroll
    for (int n = 0; n < 4; ++n) {
        const int col = n0 + wc + n * 16 + fr;
        const float bv = bias[col];
        #pragma unroll
        for (int m = 0; m < 4; ++m) {
            #pragma unroll
            for (int r = 0; r < 4; ++r) {
                const int row = m0 + wr + m * 16 + r0 + r;
                if (row < M) {
                    float v = acc[m][n][r] + bv;
                    if (RELU) v = fmaxf(v, 0.f);
                    if (OUT_BF16)
                        ((unsigned short*)Cout)[(size_t)row * N + col] = f2bf(v);
                    else
                        ((float*)Cout)[(size_t)row * N + col] = v;
                }
            }
        }
    }
}

// ---------------------------------------------------------------------------
// GEMM (N=256) + bias + residual + LayerNorm, fused. 2-phase double-buffered.
// BM=64, BN=256, BK=32, 512 threads = 8 waves (2 row x 4 col). Grid fills CUs.
// ---------------------------------------------------------------------------
template<int MIRROR>
__global__ __launch_bounds__(512) void gemm_ln(
    const unsigned short* __restrict__ A,
    const unsigned short* __restrict__ BT,
    const float* __restrict__ bias,
    const float* __restrict__ res,
    const float* __restrict__ g,
    const float* __restrict__ beta,
    float* __restrict__ outf,
    unsigned short* __restrict__ out16,
    int M, int K)
{
    __shared__ unsigned short As[2][64 * 32];
    __shared__ unsigned short Bs[2][256 * 32];
    __shared__ float2 sRed[4][64];

    const int tid  = threadIdx.x;
    const int wave = tid >> 6;
    const int lane = tid & 63;
    const int m0 = blockIdx.x * 64;
    const int wr = (wave >> 2) * 32;
    const int wc = (wave & 3) * 64;

    f32x4 acc[2][4] = {};

    auto stage = [&](int buf, int k0) {
        if (tid < 256) {   // wave-uniform branch: waves 0-3 stage A (4096 B)
            const int off  = tid * 16;
            const int row  = off >> 6;
            const int colb = off & 63;
            int ar = m0 + row; ar = (ar < M) ? ar : (M - 1);
            __builtin_amdgcn_global_load_lds(AS1U(A + (size_t)ar * K + k0 + (colb >> 1)),
                AS3U(&As[buf][(wave * 1024) >> 1]), 16, 0, 0);
        }
        #pragma unroll
        for (int p = 0; p < 2; ++p) {   // B: 16384 B, 2 passes x 512 thr x 16 B
            const int off  = p * 8192 + tid * 16;
            const int row  = off >> 6;
            const int colb = off & 63;
            __builtin_amdgcn_global_load_lds(AS1U(BT + (size_t)row * K + k0 + (colb >> 1)),
                AS3U(&Bs[buf][(p * 8192 + wave * 1024) >> 1]), 16, 0, 0);
        }
    };

    const int nt = K >> 5;
    stage(0, 0);
    __syncthreads();
    int cur = 0;
    for (int t = 0; t < nt; ++t) {
        if (t + 1 < nt) stage(cur ^ 1, (t + 1) * 32);

        const int fr = lane & 15;
        const int kb = (lane >> 4) * 8;
        short8 af[2], bf[4];
        #pragma unroll
        for (int m = 0; m < 2; ++m)
            af[m] = *reinterpret_cast<const short8*>(&As[cur][(wr + m * 16 + fr) * 32 + kb]);
        #pragma unroll
        for (int n = 0; n < 4; ++n)
            bf[n] = *reinterpret_cast<const short8*>(&Bs[cur][(wc + n * 16 + fr) * 32 + kb]);
        #pragma unroll
        for (int m = 0; m < 2; ++m)
            #pragma unroll
            for (int n = 0; n < 4; ++n)
                acc[m][n] = __builtin_amdgcn_mfma_f32_16x16x32_bf16(af[m], bf[n], acc[m][n], 0, 0, 0);

        if (t + 1 < nt) { __syncthreads(); cur ^= 1; }
    }

    // ---- epilogue: bias + residual, then row-LN over 256 cols ----
    const int fr = lane & 15;
    const int r0 = (lane >> 4) * 4;
    float biasv[4], gv[4], bev[4];
    #pragma unroll
    for (int n = 0; n < 4; ++n) {
        const int col = wc + n * 16 + fr;
        biasv[n] = bias[col]; gv[n] = g[col]; bev[n] = beta[col];
    }
    #pragma unroll
    for (int m = 0; m < 2; ++m) {
        #pragma unroll
        for (int r = 0; r < 4; ++r) {
            int row = m0 + wr + m * 16 + r0 + r;
            int rr = (row < M) ? row : (M - 1);
            const float* rp = res + (size_t)rr * 256;
            #pragma unroll
            for (int n = 0; n < 4; ++n)
                acc[m][n][r] += biasv[n] + rp[wc + n * 16 + fr];
        }
    }
    #pragma unroll
    for (int m = 0; m < 2; ++m) {
        #pragma unroll
        for (int r = 0; r < 4; ++r) {
            float sx = 0.f, sxx = 0.f;
            #pragma unroll
            for (int n = 0; n < 4; ++n) { float t = acc[m][n][r]; sx += t; sxx += t * t; }
            #pragma unroll
            for (int mask = 1; mask < 16; mask <<= 1) {
                sx  += __shfl_xor(sx, mask);
                sxx += __shfl_xor(sxx, mask);
            }
            if (fr == 0) sRed[wave & 3][wr + m * 16 + r0 + r] = make_float2(sx, sxx);
        }
    }
    __syncthreads();
    #pragma unroll
    for (int m = 0; m < 2; ++m) {
        #pragma unroll
        for (int r = 0; r < 4; ++r) {
            const int lr = wr + m * 16 + r0 + r;
            float2 a0 = sRed[0][lr], a1 = sRed[1][lr], a2 = sRed[2][lr], a3 = sRed[3][lr];
            const float S  = a0.x + a1.x + a2.x + a3.x;
            const float SS = a0.y + a1.y + a2.y + a3.y;
            const float mean = S * (1.f / 256.f);
            const float var  = SS * (1.f / 256.f) - mean * mean;
            const float rstd = rsqrtf(var + 1e-5f);
            const int row = m0 + lr;
            if (row < M) {
                #pragma unroll
                for (int n = 0; n < 4; ++n) {
                    const int col = wc + n * 16 + fr;
                    const float y = (acc[m][n][r] - mean) * rstd * gv[n] + bev[n];
                    outf[(size_t)row * 256 + col] = y;
                    if (MIRROR) out16[(size_t)row * 256 + col] = f2bf(y);
                }
            }
        }
    }
}

// ---------------------------------------------------------------------------
// Multi-scale deformable attention: one wave per query (4 / block), f32 vproj.
// ---------------------------------------------------------------------------
__global__ __launch_bounds__(256) void msdeform_kernel(
    const float* __restrict__ vproj, const float* __restrict__ offattn,
    const float* __restrict__ refp, unsigned short* __restrict__ msout)
{
    __shared__ int4   sIdx[4][8][17];   // byte offsets (idx*1024)
    __shared__ float4 sWgt[4][8][17];

    const int wave = threadIdx.x >> 6;
    const int lane = threadIdx.x & 63;
    const int bq = blockIdx.x * 4 + wave;
    if (bq >= M_) return;
    const int b = bq / LQ_;
    const int h = lane >> 3;
    const int k = lane & 7;

    const float4 o4  = *reinterpret_cast<const float4*>(offattn + (size_t)bq * 384 + h * 32 + 4 * k);
    const float2 lg2 = *reinterpret_cast<const float2*>(offattn + (size_t)bq * 384 + 256 + h * 16 + 2 * k);
    const int l = k >> 1;
    const float2 rp  = *reinterpret_cast<const float2*>(refp + (size_t)bq * 8 + 2 * l);

    const float Wf[4] = {106.f, 53.f, 27.f, 14.f};
    const float Hf[4] = {76.f, 38.f, 19.f, 10.f};
    const int   Wi[4] = {106, 53, 27, 14};
    const int   Hi[4] = {76, 38, 19, 10};
    const int   St[4] = {0, 8056, 10070, 10583};

    float mx = fmaxf(lg2.x, lg2.y);
    mx = fmaxf(mx, __shfl_xor(mx, 1));
    mx = fmaxf(mx, __shfl_xor(mx, 2));
    mx = fmaxf(mx, __shfl_xor(mx, 4));
    const float e0 = __expf(lg2.x - mx), e1 = __expf(lg2.y - mx);
    float s = e0 + e1;
    s += __shfl_xor(s, 1); s += __shfl_xor(s, 2); s += __shfl_xor(s, 4);
    const float inv = 1.f / s;

    const int W = Wi[l], H = Hi[l];
    const float Wff = Wf[l], Hff = Hf[l];
    const int base = St[l];

    #pragma unroll
    for (int pp = 0; pp < 2; ++pp) {
        const float ox = pp ? o4.z : o4.x;
        const float oy = pp ? o4.w : o4.y;
        const float aw = (pp ? e1 : e0) * inv;
        const float x = fmaf(rp.x, Wff, ox) - 0.5f;
        const float y = fmaf(rp.y, Hff, oy) - 0.5f;
        const float xf = floorf(x), yf = floorf(y);
        const float fx = x - xf, fy = y - yf;
        const int x0 = (int)xf, y0 = (int)yf;
        const float gx = 1.f - fx, gy = 1.f - fy;
        const bool vx0 = (x0 >= 0) && (x0 < W);
        const bool vx1 = (x0 + 1 >= 0) && (x0 + 1 < W);
        const bool vy0 = (y0 >= 0) && (y0 < H);
        const bool vy1 = (y0 + 1 >= 0) && (y0 + 1 < H);
        const int xc0 = min(max(x0, 0), W - 1);
        const int xc1 = min(max(x0 + 1, 0), W - 1);
        const int yr0 = min(max(y0, 0), H - 1) * W;
        const int yr1 = min(max(y0 + 1, 0), H - 1) * W;
        int4 iv; float4 wv;
        iv.x = (base + yr0 + xc0) << 10;  wv.x = (vx0 && vy0) ? gx * gy * aw : 0.f;
        iv.y = (base + yr0 + xc1) << 10;  wv.y = (vx1 && vy0) ? fx * gy * aw : 0.f;
        iv.z = (base + yr1 + xc0) << 10;  wv.z = (vx0 && vy1) ? gx * fy * aw : 0.f;
        iv.w = (base + yr1 + xc1) << 10;  wv.w = (vx1 && vy1) ? fx * fy * aw : 0.f;
        sIdx[wave][h][2 * k + pp] = iv;
        sWgt[wave][h][2 * k + pp] = wv;
    }

    const int j = k;
    const char* vb = (const char*)(vproj + (size_t)b * LQ_ * 256 + h * 32 + j * 4);
    float4 acc = make_float4(0.f, 0.f, 0.f, 0.f);
    #pragma unroll
    for (int p = 0; p < 16; ++p) {
        const int4   iv = sIdx[wave][h][p];
        const float4 wv = sWgt[wave][h][p];
        {
            float4 v = *reinterpret_cast<const float4*>(vb + (unsigned)iv.x);
            acc.x = fmaf(wv.x, v.x, acc.x); acc.y = fmaf(wv.x, v.y, acc.y);
            acc.z = fmaf(wv.x, v.z, acc.z); acc.w = fmaf(wv.x, v.w, acc.w);
        }
        {
            float4 v = *reinterpret_cast<const float4*>(vb + (unsigned)iv.y);
            acc.x = fmaf(wv.y, v.x, acc.x); acc.y = fmaf(wv.y, v.y, acc.y);
            acc.z = fmaf(wv.y, v.z, acc.z); acc.w = fmaf(wv.y, v.w, acc.w);
        }
        {
            float4 v = *reinterpret_cast<const float4*>(vb + (unsigned)iv.z);
            acc.x = fmaf(wv.z, v.x, acc.x); acc.y = fmaf(wv.z, v.y, acc.y);
            acc.z = fmaf(wv.z, v.z, acc.z); acc.w = fmaf(wv.z, v.w, acc.w);
        }
        {
            float4 v = *reinterpret_cast<const float4*>(vb + (unsigned)iv.w);
            acc.x = fmaf(wv.w, v.x, acc.x); acc.y = fmaf(wv.w, v.y, acc.y);
            acc.z = fmaf(wv.w, v.z, acc.z); acc.w = fmaf(wv.w, v.w, acc.w);
        }
    }
    us4 r = { f2bf(acc.x), f2bf(acc.y), f2bf(acc.z), f2bf(acc.w) };
    *reinterpret_cast<us4*>(msout + (size_t)bq * 256 + h * 32 + j * 4) = r;
}

// ---------------------------------------------------------------------------
extern "C" void kernel_launch(void* const* d_in, const int* in_sizes, int n_in,
                              void* d_out, int out_size, void* d_ws, size_t ws_size,
                              hipStream_t stream) {
    const float* query = (const float*)d_in[0];
    const float* qpos  = (const float*)d_in[1];
    const float* value = (const float*)d_in[2];
    const float* refp  = (const float*)d_in[3];
    const float* W_off  = (const float*)d_in[6];
    const float* b_off  = (const float*)d_in[7];
    const float* W_attn = (const float*)d_in[8];
    const float* b_attn = (const float*)d_in[9];
    const float* W_v    = (const float*)d_in[10];
    const float* b_v    = (const float*)d_in[11];
    const float* W_out  = (const float*)d_in[12];
    const float* b_out  = (const float*)d_in[13];
    const float* ln1_g  = (const float*)d_in[14];
    const float* ln1_b  = (const float*)d_in[15];
    const float* W1     = (const float*)d_in[16];
    const float* b1     = (const float*)d_in[17];
    const float* W2     = (const float*)d_in[18];
    const float* b2     = (const float*)d_in[19];
    const float* ln2_g  = (const float*)d_in[20];
    const float* ln2_b  = (const float*)d_in[21];
    float* out = (float*)d_out;

    // ---- workspace layout ----
    unsigned short* WvT   = (unsigned short*)d_ws;
    unsigned short* WoaT  = WvT   + 65536;    // 384 x 256  (off | attn)
    unsigned short* WoutT = WoaT  + 98304;
    unsigned short* W1T   = WoutT + 65536;    // 1024 x 256
    unsigned short* W2T   = W1T   + 262144;   // 256 x 1024
    float* b_oa = (float*)(W2T + 262144);     // 384 f32
    uint8_t* base = (uint8_t*)(b_oa + 384);
    base = (uint8_t*)(((uintptr_t)base + 255) & ~(uintptr_t)255);

    const size_t A = (size_t)M_ * D_;
    unsigned short* R_v16  = (unsigned short*)base;          // value bf16 -> q1 bf16 mirror
    unsigned short* R_q16  = R_v16 + A;                      // q bf16 -> ms16
    float* R_vp  = (float*)(R_q16 + A);                      // vproj f32 (gather src)
    float* R_oa  = R_vp + A;                                 // off|attn (M,384)
    float* R_q1  = R_oa + (size_t)M_ * 384;                  // q1 f32
    unsigned short* R_h16 = (unsigned short*)(R_q1 + A);     // FFN hidden bf16 (M,1024)

    const dim3 blk(256);
    auto cdiv = [](size_t a, size_t b) { return (unsigned)((a + b - 1) / b); };

    prep_weights_kernel<<<cdiv(754048, 256), blk, 0, stream>>>(
        W_v, W_off, W_attn, W_out, W1, W2, b_off, b_attn,
        WvT, WoaT, WoutT, W1T, W2T, b_oa);
    prep_acts_kernel<<<cdiv(2 * (A / 4), 256), blk, 0, stream>>>(
        value, query, qpos, R_v16, R_q16, A / 4);

    const unsigned MT = (M_ + 127) / 128;   // 168
    // vproj f32 (gather source)
    gemm_mfma<0, 0><<<dim3(2, MT), blk, 0, stream>>>(R_v16, WvT, b_v, R_vp, M_, 256, 256);
    // off|attn fused (f32, N=384)
    gemm_mfma<0, 0><<<dim3(3, MT), blk, 0, stream>>>(R_q16, WoaT, b_oa, R_oa, M_, 384, 256);
    // deformable attention -> ms16 (overwrites R_q16, dead)
    msdeform_kernel<<<dim3(cdiv(M_, 4)), blk, 0, stream>>>(R_vp, R_oa, refp, R_q16);
    // q1 = LN(query + ms16@WoutT^T + b_out): f32 -> R_q1, bf16 -> R_v16 (dead)
    gemm_ln<1><<<dim3(cdiv(M_, 64)), dim3(512), 0, stream>>>(
        R_q16, WoutT, b_out, query, ln1_g, ln1_b, R_q1, R_v16, M_, 256);
    // h = relu(q1b @ W1T^T) bf16
    gemm_mfma<1, 1><<<dim3(8, MT), blk, 0, stream>>>(R_v16, W1T, b1, R_h16, M_, 1024, 256);
    // out = LN(q1 + h@W2T^T + b2)
    gemm_ln<0><<<dim3(cdiv(M_, 64)), dim3(512), 0, stream>>>(
        R_h16, W2T, b2, R_q1, ln2_g, ln2_b, out, nullptr, M_, 1024);
}

// Round 6
// 193.343 us; speedup vs baseline: 4.2882x; 1.0436x over previous
//
#include <hip/hip_runtime.h>
#include <math.h>

#define B_   2
#define LQ_  10723
#define D_   256
#define NH_  8
#define HD_  32
#define NL_  4
#define NP_  4
#define DFF_ 1024
#define M_   (B_ * LQ_)   // 21446

typedef __attribute__((ext_vector_type(4))) float f32x4;
typedef __attribute__((ext_vector_type(8))) short short8;
typedef __attribute__((ext_vector_type(4))) unsigned short us4;

__device__ __forceinline__ unsigned short f2bf(float f) {
    union { float f; unsigned int u; } x; x.f = f;
    unsigned int r = x.u + 0x7FFF + ((x.u >> 16) & 1);   // RNE
    return (unsigned short)(r >> 16);
}
__device__ __forceinline__ float bf2f(unsigned short u) {
    union { unsigned int u; float f; } x; x.u = (unsigned int)u << 16;
    return x.f;
}

#define AS3U(p) ((__attribute__((address_space(3))) unsigned int*)(uintptr_t)(p))
#define AS1U(p) ((const __attribute__((address_space(1))) unsigned int*)(uintptr_t)(p))

// ---------------------------------------------------------------------------
// One-shot weight prep: f32 (K,N) -> bf16 (N,K); off|attn fused; b_oa concat.
// ---------------------------------------------------------------------------
__global__ __launch_bounds__(256) void prep_weights_kernel(
    const float* __restrict__ Wv, const float* __restrict__ Woff,
    const float* __restrict__ Wattn, const float* __restrict__ Wout,
    const float* __restrict__ W1, const float* __restrict__ W2,
    const float* __restrict__ b_off, const float* __restrict__ b_attn,
    unsigned short* __restrict__ WvT, unsigned short* __restrict__ WoaT,
    unsigned short* __restrict__ WoutT, unsigned short* __restrict__ W1T,
    unsigned short* __restrict__ W2T, float* __restrict__ b_oa)
{
    int idx = blockIdx.x * 256 + threadIdx.x;
    if (idx < 65536) {
        int n = idx >> 8, k = idx & 255;
        WvT[idx] = f2bf(Wv[k * 256 + n]);
    } else if (idx < 163840) {
        int l = idx - 65536; int n = l >> 8, k = l & 255;
        WoaT[l] = f2bf(n < 256 ? Woff[k * 256 + n] : Wattn[k * 128 + (n - 256)]);
    } else if (idx < 229376) {
        int l = idx - 163840; int n = l >> 8, k = l & 255;
        WoutT[l] = f2bf(Wout[k * 256 + n]);
    } else if (idx < 491520) {
        int l = idx - 229376; int n = l >> 8, k = l & 255;
        W1T[l] = f2bf(W1[k * 1024 + n]);
    } else if (idx < 753664) {
        int l = idx - 491520; int n = l >> 10, k = l & 1023;
        W2T[l] = f2bf(W2[k * 256 + n]);
    } else if (idx < 754048) {
        int l = idx - 753664;
        b_oa[l] = (l < 256) ? b_off[l] : b_attn[l - 256];
    }
}

// value -> bf16  and  q = bf16(query + qpos)
__global__ __launch_bounds__(256) void prep_acts_kernel(
    const float* __restrict__ value, const float* __restrict__ query,
    const float* __restrict__ qpos,
    unsigned short* __restrict__ v16, unsigned short* __restrict__ q16, size_t n4)
{
    size_t i = (size_t)blockIdx.x * 256 + threadIdx.x;
    if (i < n4) {
        float4 v = reinterpret_cast<const float4*>(value)[i];
        us4 r = { f2bf(v.x), f2bf(v.y), f2bf(v.z), f2bf(v.w) };
        reinterpret_cast<us4*>(v16)[i] = r;
    } else if (i < 2 * n4) {
        size_t j = i - n4;
        float4 va = reinterpret_cast<const float4*>(query)[j];
        float4 vb = reinterpret_cast<const float4*>(qpos)[j];
        us4 r = { f2bf(va.x + vb.x), f2bf(va.y + vb.y), f2bf(va.z + vb.z), f2bf(va.w + vb.w) };
        reinterpret_cast<us4*>(q16)[j] = r;
    }
}

// ---------------------------------------------------------------------------
// MFMA bf16 GEMM, 2-phase double-buffered.
// OUT_MODE: 0 = f32 row-major, 1 = bf16 row-major, 2 = bf16 head-major
//           (vproj gather layout: [b][h][lv][32], N must be 256)
// ---------------------------------------------------------------------------
template<int RELU, int OUT_MODE>
__global__ __launch_bounds__(256) void gemm_mfma(
    const unsigned short* __restrict__ A,
    const unsigned short* __restrict__ BT,
    const float* __restrict__ bias,
    void* __restrict__ Cout,
    int M, int N, int K)
{
    __shared__ unsigned short As[2][128 * 32];
    __shared__ unsigned short Bs[2][128 * 32];

    const int tid  = threadIdx.x;
    const int wave = tid >> 6;
    const int lane = tid & 63;
    const int m0 = blockIdx.y * 128;
    const int n0 = blockIdx.x * 128;
    const int wr = (wave >> 1) * 64;
    const int wc = (wave & 1) * 64;

    f32x4 acc[4][4] = {};
    const int soff = wave * 1024 + lane * 16;

    auto stage = [&](int buf, int k0) {
        #pragma unroll
        for (int p = 0; p < 2; ++p) {
            const int off  = p * 4096 + soff;
            const int row  = off >> 6;
            const int colb = off & 63;
            int ar = m0 + row; ar = (ar < M) ? ar : (M - 1);
            __builtin_amdgcn_global_load_lds(AS1U(A + (size_t)ar * K + k0 + (colb >> 1)),
                AS3U(&As[buf][(p * 4096 + wave * 1024) >> 1]), 16, 0, 0);
            __builtin_amdgcn_global_load_lds(AS1U(BT + (size_t)(n0 + row) * K + k0 + (colb >> 1)),
                AS3U(&Bs[buf][(p * 4096 + wave * 1024) >> 1]), 16, 0, 0);
        }
    };

    const int nt = K >> 5;
    stage(0, 0);
    __syncthreads();
    int cur = 0;
    for (int t = 0; t < nt; ++t) {
        if (t + 1 < nt) stage(cur ^ 1, (t + 1) * 32);

        const int fr = lane & 15;
        const int kb = (lane >> 4) * 8;
        short8 af[4], bf[4];
        #pragma unroll
        for (int m = 0; m < 4; ++m)
            af[m] = *reinterpret_cast<const short8*>(&As[cur][(wr + m * 16 + fr) * 32 + kb]);
        #pragma unroll
        for (int n = 0; n < 4; ++n)
            bf[n] = *reinterpret_cast<const short8*>(&Bs[cur][(wc + n * 16 + fr) * 32 + kb]);
        #pragma unroll
        for (int m = 0; m < 4; ++m)
            #pragma unroll
            for (int n = 0; n < 4; ++n)
                acc[m][n] = __builtin_amdgcn_mfma_f32_16x16x32_bf16(af[m], bf[n], acc[m][n], 0, 0, 0);

        if (t + 1 < nt) { __syncthreads(); cur ^= 1; }
    }

    const int fr = lane & 15;
    const int r0 = (lane >> 4) * 4;
    #pragma unroll
    for (int n = 0; n < 4; ++n) {
        const int col = n0 + wc + n * 16 + fr;
        const float bv = bias[col];
        #pragma unroll
        for (int m = 0; m < 4; ++m) {
            #pragma unroll
            for (int r = 0; r < 4; ++r) {
                const int row = m0 + wr + m * 16 + r0 + r;
                if (row < M) {
                    float v = acc[m][n][r] + bv;
                    if (RELU) v = fmaxf(v, 0.f);
                    if (OUT_MODE == 0) {
                        ((float*)Cout)[(size_t)row * N + col] = v;
                    } else if (OUT_MODE == 1) {
                        ((unsigned short*)Cout)[(size_t)row * N + col] = f2bf(v);
                    } else {
                        // head-major: [b][h][lv][32]
                        const int bb = (row >= LQ_) ? 1 : 0;
                        const int lv = row - bb * LQ_;
                        const int hh = col >> 5, dd = col & 31;
                        ((unsigned short*)Cout)[(((size_t)bb * NH_ + hh) * LQ_ + lv) * 32 + dd] = f2bf(v);
                    }
                }
            }
        }
    }
}

// ---------------------------------------------------------------------------
// GEMM (N=256) + bias + residual + LayerNorm, fused. 2-phase double-buffered.
// BM=64, BN=256, BK=32, 512 threads = 8 waves (2 row x 4 col).
// ---------------------------------------------------------------------------
template<int MIRROR>
__global__ __launch_bounds__(512) void gemm_ln(
    const unsigned short* __restrict__ A,
    const unsigned short* __restrict__ BT,
    const float* __restrict__ bias,
    const float* __restrict__ res,
    const float* __restrict__ g,
    const float* __restrict__ beta,
    float* __restrict__ outf,
    unsigned short* __restrict__ out16,
    int M, int K)
{
    __shared__ unsigned short As[2][64 * 32];
    __shared__ unsigned short Bs[2][256 * 32];
    __shared__ float2 sRed[4][64];

    const int tid  = threadIdx.x;
    const int wave = tid >> 6;
    const int lane = tid & 63;
    const int m0 = blockIdx.x * 64;
    const int wr = (wave >> 2) * 32;
    const int wc = (wave & 3) * 64;

    f32x4 acc[2][4] = {};

    auto stage = [&](int buf, int k0) {
        if (tid < 256) {
            const int off  = tid * 16;
            const int row  = off >> 6;
            const int colb = off & 63;
            int ar = m0 + row; ar = (ar < M) ? ar : (M - 1);
            __builtin_amdgcn_global_load_lds(AS1U(A + (size_t)ar * K + k0 + (colb >> 1)),
                AS3U(&As[buf][(wave * 1024) >> 1]), 16, 0, 0);
        }
        #pragma unroll
        for (int p = 0; p < 2; ++p) {
            const int off  = p * 8192 + tid * 16;
            const int row  = off >> 6;
            const int colb = off & 63;
            __builtin_amdgcn_global_load_lds(AS1U(BT + (size_t)row * K + k0 + (colb >> 1)),
                AS3U(&Bs[buf][(p * 8192 + wave * 1024) >> 1]), 16, 0, 0);
        }
    };

    const int nt = K >> 5;
    stage(0, 0);
    __syncthreads();
    int cur = 0;
    for (int t = 0; t < nt; ++t) {
        if (t + 1 < nt) stage(cur ^ 1, (t + 1) * 32);

        const int fr = lane & 15;
        const int kb = (lane >> 4) * 8;
        short8 af[2], bf[4];
        #pragma unroll
        for (int m = 0; m < 2; ++m)
            af[m] = *reinterpret_cast<const short8*>(&As[cur][(wr + m * 16 + fr) * 32 + kb]);
        #pragma unroll
        for (int n = 0; n < 4; ++n)
            bf[n] = *reinterpret_cast<const short8*>(&Bs[cur][(wc + n * 16 + fr) * 32 + kb]);
        #pragma unroll
        for (int m = 0; m < 2; ++m)
            #pragma unroll
            for (int n = 0; n < 4; ++n)
                acc[m][n] = __builtin_amdgcn_mfma_f32_16x16x32_bf16(af[m], bf[n], acc[m][n], 0, 0, 0);

        if (t + 1 < nt) { __syncthreads(); cur ^= 1; }
    }

    const int fr = lane & 15;
    const int r0 = (lane >> 4) * 4;
    float biasv[4], gv[4], bev[4];
    #pragma unroll
    for (int n = 0; n < 4; ++n) {
        const int col = wc + n * 16 + fr;
        biasv[n] = bias[col]; gv[n] = g[col]; bev[n] = beta[col];
    }
    #pragma unroll
    for (int m = 0; m < 2; ++m) {
        #pragma unroll
        for (int r = 0; r < 4; ++r) {
            int row = m0 + wr + m * 16 + r0 + r;
            int rr = (row < M) ? row : (M - 1);
            const float* rp = res + (size_t)rr * 256;
            #pragma unroll
            for (int n = 0; n < 4; ++n)
                acc[m][n][r] += biasv[n] + rp[wc + n * 16 + fr];
        }
    }
    #pragma unroll
    for (int m = 0; m < 2; ++m) {
        #pragma unroll
        for (int r = 0; r < 4; ++r) {
            float sx = 0.f, sxx = 0.f;
            #pragma unroll
            for (int n = 0; n < 4; ++n) { float t = acc[m][n][r]; sx += t; sxx += t * t; }
            #pragma unroll
            for (int mask = 1; mask < 16; mask <<= 1) {
                sx  += __shfl_xor(sx, mask);
                sxx += __shfl_xor(sxx, mask);
            }
            if (fr == 0) sRed[wave & 3][wr + m * 16 + r0 + r] = make_float2(sx, sxx);
        }
    }
    __syncthreads();
    #pragma unroll
    for (int m = 0; m < 2; ++m) {
        #pragma unroll
        for (int r = 0; r < 4; ++r) {
            const int lr = wr + m * 16 + r0 + r;
            float2 a0 = sRed[0][lr], a1 = sRed[1][lr], a2 = sRed[2][lr], a3 = sRed[3][lr];
            const float S  = a0.x + a1.x + a2.x + a3.x;
            const float SS = a0.y + a1.y + a2.y + a3.y;
            const float mean = S * (1.f / 256.f);
            const float var  = SS * (1.f / 256.f) - mean * mean;
            const float rstd = rsqrtf(var + 1e-5f);
            const int row = m0 + lr;
            if (row < M) {
                #pragma unroll
                for (int n = 0; n < 4; ++n) {
                    const int col = wc + n * 16 + fr;
                    const float y = (acc[m][n][r] - mean) * rstd * gv[n] + bev[n];
                    outf[(size_t)row * 256 + col] = y;
                    if (MIRROR) out16[(size_t)row * 256 + col] = f2bf(y);
                }
            }
        }
    }
}

// ---------------------------------------------------------------------------
// Multi-scale deformable attention, XCD-local by head.
// Block = (query-chunk qc, bh = b*8+h); blockIdx.x = qc*16 + bh so that
// bh%8 == h maps head -> XCD (round-robin heuristic): per-XCD gather
// footprint = 2 * 686 KB (one head's bf16 value field per batch) -> L2-hit.
// 256 threads = 4 waves; wave handles 8 queries (8 lanes each).
// vproj_h: bf16 [b][h][lv][32] (head-major, written by gemm_mfma OUT_MODE=2).
// ---------------------------------------------------------------------------
__global__ __launch_bounds__(256) void msdeform_kernel(
    const unsigned short* __restrict__ vproj_h, const float* __restrict__ offattn,
    const float* __restrict__ refp, unsigned short* __restrict__ msout)
{
    __shared__ int4   sIdx[4][8][17];   // [wave][query-in-wave][point] byte-offsets/64B units
    __shared__ float4 sWgt[4][8][17];

    const int bh = blockIdx.x & 15;          // b*8 + h
    const int qc = blockIdx.x >> 4;
    const int b  = bh >> 3;
    const int h  = bh & 7;
    const int wave = threadIdx.x >> 6;
    const int lane = threadIdx.x & 63;
    const int qw = lane >> 3;                // query within wave
    const int k  = lane & 7;                 // point-pair / channel-quad
    const int lv = qc * 32 + wave * 8 + qw;  // query within batch
    if (lv >= LQ_) return;
    const int bq = b * LQ_ + lv;

    // ---- phase 1: weights & indices (per (q, k): points 2k, 2k+1) ----
    const float4 o4  = *reinterpret_cast<const float4*>(offattn + (size_t)bq * 384 + h * 32 + 4 * k);
    const float2 lg2 = *reinterpret_cast<const float2*>(offattn + (size_t)bq * 384 + 256 + h * 16 + 2 * k);
    const int l = k >> 1;
    const float2 rp  = *reinterpret_cast<const float2*>(refp + (size_t)bq * 8 + 2 * l);

    const float Wf[4] = {106.f, 53.f, 27.f, 14.f};
    const float Hf[4] = {76.f, 38.f, 19.f, 10.f};
    const int   Wi[4] = {106, 53, 27, 14};
    const int   Hi[4] = {76, 38, 19, 10};
    const int   St[4] = {0, 8056, 10070, 10583};

    float mx = fmaxf(lg2.x, lg2.y);
    mx = fmaxf(mx, __shfl_xor(mx, 1));
    mx = fmaxf(mx, __shfl_xor(mx, 2));
    mx = fmaxf(mx, __shfl_xor(mx, 4));
    const float e0 = __expf(lg2.x - mx), e1 = __expf(lg2.y - mx);
    float s = e0 + e1;
    s += __shfl_xor(s, 1); s += __shfl_xor(s, 2); s += __shfl_xor(s, 4);
    const float inv = 1.f / s;

    const int W = Wi[l], H = Hi[l];
    const float Wff = Wf[l], Hff = Hf[l];
    const int base = St[l];

    #pragma unroll
    for (int pp = 0; pp < 2; ++pp) {
        const float ox = pp ? o4.z : o4.x;
        const float oy = pp ? o4.w : o4.y;
        const float aw = (pp ? e1 : e0) * inv;
        const float x = fmaf(rp.x, Wff, ox) - 0.5f;
        const float y = fmaf(rp.y, Hff, oy) - 0.5f;
        const float xf = floorf(x), yf = floorf(y);
        const float fx = x - xf, fy = y - yf;
        const int x0 = (int)xf, y0 = (int)yf;
        const float gx = 1.f - fx, gy = 1.f - fy;
        const bool vx0 = (x0 >= 0) && (x0 < W);
        const bool vx1 = (x0 + 1 >= 0) && (x0 + 1 < W);
        const bool vy0 = (y0 >= 0) && (y0 < H);
        const bool vy1 = (y0 + 1 >= 0) && (y0 + 1 < H);
        const int xc0 = min(max(x0, 0), W - 1);
        const int xc1 = min(max(x0 + 1, 0), W - 1);
        const int yr0 = min(max(y0, 0), H - 1) * W;
        const int yr1 = min(max(y0 + 1, 0), H - 1) * W;
        int4 iv; float4 wv;
        iv.x = (base + yr0 + xc0) << 6;  wv.x = (vx0 && vy0) ? gx * gy * aw : 0.f;
        iv.y = (base + yr0 + xc1) << 6;  wv.y = (vx1 && vy0) ? fx * gy * aw : 0.f;
        iv.z = (base + yr1 + xc0) << 6;  wv.z = (vx0 && vy1) ? gx * fy * aw : 0.f;
        iv.w = (base + yr1 + xc1) << 6;  wv.w = (vx1 && vy1) ? fx * fy * aw : 0.f;
        sIdx[wave][qw][2 * k + pp] = iv;
        sWgt[wave][qw][2 * k + pp] = wv;
    }

    // ---- phase 2: gather + accumulate (lane: query qw, channels 4k..4k+3) ----
    const char* vb = (const char*)(vproj_h + (size_t)bh * LQ_ * 32) + k * 8;
    float4 acc = make_float4(0.f, 0.f, 0.f, 0.f);
    #pragma unroll
    for (int p = 0; p < 16; ++p) {
        const int4   iv = sIdx[wave][qw][p];
        const float4 wv = sWgt[wave][qw][p];
        {
            us4 v = *reinterpret_cast<const us4*>(vb + (unsigned)iv.x);
            acc.x = fmaf(wv.x, bf2f(v.x), acc.x); acc.y = fmaf(wv.x, bf2f(v.y), acc.y);
            acc.z = fmaf(wv.x, bf2f(v.z), acc.z); acc.w = fmaf(wv.x, bf2f(v.w), acc.w);
        }
        {
            us4 v = *reinterpret_cast<const us4*>(vb + (unsigned)iv.y);
            acc.x = fmaf(wv.y, bf2f(v.x), acc.x); acc.y = fmaf(wv.y, bf2f(v.y), acc.y);
            acc.z = fmaf(wv.y, bf2f(v.z), acc.z); acc.w = fmaf(wv.y, bf2f(v.w), acc.w);
        }
        {
            us4 v = *reinterpret_cast<const us4*>(vb + (unsigned)iv.z);
            acc.x = fmaf(wv.z, bf2f(v.x), acc.x); acc.y = fmaf(wv.z, bf2f(v.y), acc.y);
            acc.z = fmaf(wv.z, bf2f(v.z), acc.z); acc.w = fmaf(wv.z, bf2f(v.w), acc.w);
        }
        {
            us4 v = *reinterpret_cast<const us4*>(vb + (unsigned)iv.w);
            acc.x = fmaf(wv.w, bf2f(v.x), acc.x); acc.y = fmaf(wv.w, bf2f(v.y), acc.y);
            acc.z = fmaf(wv.w, bf2f(v.z), acc.z); acc.w = fmaf(wv.w, bf2f(v.w), acc.w);
        }
    }
    us4 r = { f2bf(acc.x), f2bf(acc.y), f2bf(acc.z), f2bf(acc.w) };
    *reinterpret_cast<us4*>(msout + (size_t)bq * 256 + h * 32 + k * 4) = r;
}

// ---------------------------------------------------------------------------
extern "C" void kernel_launch(void* const* d_in, const int* in_sizes, int n_in,
                              void* d_out, int out_size, void* d_ws, size_t ws_size,
                              hipStream_t stream) {
    const float* query = (const float*)d_in[0];
    const float* qpos  = (const float*)d_in[1];
    const float* value = (const float*)d_in[2];
    const float* refp  = (const float*)d_in[3];
    const float* W_off  = (const float*)d_in[6];
    const float* b_off  = (const float*)d_in[7];
    const float* W_attn = (const float*)d_in[8];
    const float* b_attn = (const float*)d_in[9];
    const float* W_v    = (const float*)d_in[10];
    const float* b_v    = (const float*)d_in[11];
    const float* W_out  = (const float*)d_in[12];
    const float* b_out  = (const float*)d_in[13];
    const float* ln1_g  = (const float*)d_in[14];
    const float* ln1_b  = (const float*)d_in[15];
    const float* W1     = (const float*)d_in[16];
    const float* b1     = (const float*)d_in[17];
    const float* W2     = (const float*)d_in[18];
    const float* b2     = (const float*)d_in[19];
    const float* ln2_g  = (const float*)d_in[20];
    const float* ln2_b  = (const float*)d_in[21];
    float* out = (float*)d_out;

    // ---- workspace layout ----
    unsigned short* WvT   = (unsigned short*)d_ws;
    unsigned short* WoaT  = WvT   + 65536;    // 384 x 256  (off | attn)
    unsigned short* WoutT = WoaT  + 98304;
    unsigned short* W1T   = WoutT + 65536;    // 1024 x 256
    unsigned short* W2T   = W1T   + 262144;   // 256 x 1024
    float* b_oa = (float*)(W2T + 262144);     // 384 f32
    uint8_t* base = (uint8_t*)(b_oa + 384);
    base = (uint8_t*)(((uintptr_t)base + 255) & ~(uintptr_t)255);

    const size_t A = (size_t)M_ * D_;
    unsigned short* R_v16  = (unsigned short*)base;          // value bf16 -> q1 bf16 mirror
    unsigned short* R_q16  = R_v16 + A;                      // q bf16 -> ms16
    unsigned short* R_vph  = R_q16 + A;                      // vproj bf16 head-major
    float* R_oa  = (float*)(R_vph + A);                      // off|attn (M,384)
    float* R_q1  = R_oa + (size_t)M_ * 384;                  // q1 f32
    unsigned short* R_h16 = (unsigned short*)(R_q1 + A);     // FFN hidden bf16 (M,1024)

    const dim3 blk(256);
    auto cdiv = [](size_t a, size_t b) { return (unsigned)((a + b - 1) / b); };

    prep_weights_kernel<<<cdiv(754048, 256), blk, 0, stream>>>(
        W_v, W_off, W_attn, W_out, W1, W2, b_off, b_attn,
        WvT, WoaT, WoutT, W1T, W2T, b_oa);
    prep_acts_kernel<<<cdiv(2 * (A / 4), 256), blk, 0, stream>>>(
        value, query, qpos, R_v16, R_q16, A / 4);

    const unsigned MT = (M_ + 127) / 128;   // 168
    // vproj -> bf16 head-major (gather layout)
    gemm_mfma<0, 2><<<dim3(2, MT), blk, 0, stream>>>(R_v16, WvT, b_v, R_vph, M_, 256, 256);
    // off|attn fused (f32, N=384)
    gemm_mfma<0, 0><<<dim3(3, MT), blk, 0, stream>>>(R_q16, WoaT, b_oa, R_oa, M_, 384, 256);
    // deformable attention -> ms16 (overwrites R_q16, dead)
    const unsigned nQC = cdiv(LQ_, 32);   // 336
    msdeform_kernel<<<dim3(nQC * 16), blk, 0, stream>>>(R_vph, R_oa, refp, R_q16);
    // q1 = LN(query + ms16@WoutT^T + b_out): f32 -> R_q1, bf16 -> R_v16 (dead)
    gemm_ln<1><<<dim3(cdiv(M_, 64)), dim3(512), 0, stream>>>(
        R_q16, WoutT, b_out, query, ln1_g, ln1_b, R_q1, R_v16, M_, 256);
    // h = relu(q1b @ W1T^T) bf16
    gemm_mfma<1, 1><<<dim3(8, MT), blk, 0, stream>>>(R_v16, W1T, b1, R_h16, M_, 1024, 256);
    // out = LN(q1 + h@W2T^T + b2)
    gemm_ln<0><<<dim3(cdiv(M_, 64)), dim3(512), 0, stream>>>(
        R_h16, W2T, b2, R_q1, ln2_g, ln2_b, out, nullptr, M_, 1024);
}